// Round 13
// baseline (577.671 us; speedup 1.0000x reference)
//
#include <hip/hip_runtime.h>
#include <math.h>

// ---- problem constants ----
#define NB    8        // batch
#define LSEQ  2048     // seq len
#define TKN   16384    // NB*LSEQ tokens
#define DM    256      // d_model
#define DI    512      // d_inner
#define DS    64       // d_state
#define DIP   1153     // 2*DI + 2*DS + 1
#define DIPP  1160     // padded row stride for zx (bf16)
#define CDIM  640      // DI + 2*DS
#define NL    4
#define NC    16       // scan chunks
#define CL    128      // LSEQ/NC
#define VOC   100

typedef short bf16x8 __attribute__((ext_vector_type(8)));
typedef short bf16x4 __attribute__((ext_vector_type(4)));
typedef float f32x4  __attribute__((ext_vector_type(4)));
typedef unsigned short ushort_t;

__device__ __forceinline__ unsigned short f2bf(float f) {
  unsigned int u = __float_as_uint(f);
  unsigned int r = u + 0x7FFFu + ((u >> 16) & 1u);   // RNE
  return (unsigned short)(r >> 16);
}
__device__ __forceinline__ float bf2f(unsigned short u) {
  return __uint_as_float(((unsigned int)u) << 16);
}

// convert fp32 weights -> bf16 once per call
__global__ __launch_bounds__(256) void convert_w(const float* __restrict__ ipw,
    const float* __restrict__ opw, ushort_t* __restrict__ wbi, ushort_t* __restrict__ wbo) {
  const int n1 = NL * DIP * DM;
  const int n2 = NL * DM * DI;
  int i4 = (blockIdx.x * 256 + threadIdx.x) * 4;
  if (i4 < n1) {
    float4 v = *(const float4*)(ipw + i4);
    bf16x4 o; o[0] = (short)f2bf(v.x); o[1] = (short)f2bf(v.y);
    o[2] = (short)f2bf(v.z); o[3] = (short)f2bf(v.w);
    *(bf16x4*)(wbi + i4) = o;
  } else {
    int j = i4 - n1;
    if (j < n2) {
      float4 v = *(const float4*)(opw + j);
      bf16x4 o; o[0] = (short)f2bf(v.x); o[1] = (short)f2bf(v.y);
      o[2] = (short)f2bf(v.z); o[3] = (short)f2bf(v.w);
      *(bf16x4*)(wbo + j) = o;
    }
  }
}

// layer 0 only: resid = embed gather; hn = bf16(rmsnorm(resid)*w). One wave/token.
__global__ __launch_bounds__(256) void embed_rmsnorm(float* __restrict__ resid,
    ushort_t* __restrict__ hn, const float* __restrict__ w,
    const int* __restrict__ ids, const float* __restrict__ embed) {
  int wave = threadIdx.x >> 6, lane = threadIdx.x & 63;
  int t = blockIdx.x * 4 + wave;
  size_t o = (size_t)t * DM + lane * 4;
  int id = ids[t];
  float4 r4 = *(const float4*)&embed[(size_t)id * DM + lane * 4];
  *(float4*)&resid[o] = r4;
  float ss = r4.x * r4.x + r4.y * r4.y + r4.z * r4.z + r4.w * r4.w;
  #pragma unroll
  for (int m = 32; m >= 1; m >>= 1) ss += __shfl_xor(ss, m, 64);
  float sc = rsqrtf(ss * (1.f / DM) + 1e-5f);
  float4 w4 = *(const float4*)&w[lane * 4];
  bf16x4 o4;
  o4[0] = (short)f2bf(r4.x * sc * w4.x);
  o4[1] = (short)f2bf(r4.y * sc * w4.y);
  o4[2] = (short)f2bf(r4.z * sc * w4.z);
  o4[3] = (short)f2bf(r4.w * sc * w4.w);
  *(bf16x4*)&hn[o] = o4;
}

// ---------------- bf16 MFMA GEMM (A bf16, B bf16), BK=64 ----------------
#define LSTR  40
#define LSTR2 72
__global__ __launch_bounds__(256) void gemm_nt_bf16(const ushort_t* __restrict__ A,
    const ushort_t* __restrict__ Bw, ushort_t* __restrict__ C, int N, int K, int ldc) {
  __shared__ short sA[128 * LSTR2];
  __shared__ short sB[128 * LSTR2];
  int tid = threadIdx.x;
  int bn = blockIdx.x * 128;
  int bm = blockIdx.y * 128;
  int wave = tid >> 6, lane = tid & 63;
  int wm = (wave >> 1) * 64, wn = (wave & 1) * 64;
  int q = lane >> 4, c = lane & 15;

  f32x4 acc[4][4];
  #pragma unroll
  for (int i = 0; i < 4; ++i)
    #pragma unroll
    for (int j = 0; j < 4; ++j) acc[i][j] = (f32x4)0.f;

  int sr = tid >> 1;
  int sc = (tid & 1) * 32;
  const ushort_t* Ag = A + (size_t)(bm + sr) * K + sc;
  const ushort_t* Bg = Bw + (size_t)(bn + sr) * K + sc;
  bool bok = (bn + sr) < N;
  short* sAp = &sA[sr * LSTR2 + sc];
  short* sBp = &sB[sr * LSTR2 + sc];

  for (int k0 = 0; k0 < K; k0 += 64) {
    bf16x8 a0 = *(const bf16x8*)(Ag + k0);
    bf16x8 a1 = *(const bf16x8*)(Ag + k0 + 8);
    bf16x8 a2 = *(const bf16x8*)(Ag + k0 + 16);
    bf16x8 a3 = *(const bf16x8*)(Ag + k0 + 24);
    bf16x8 b0 = (bf16x8)(short)0, b1 = (bf16x8)(short)0;
    bf16x8 b2 = (bf16x8)(short)0, b3 = (bf16x8)(short)0;
    if (bok) {
      b0 = *(const bf16x8*)(Bg + k0);
      b1 = *(const bf16x8*)(Bg + k0 + 8);
      b2 = *(const bf16x8*)(Bg + k0 + 16);
      b3 = *(const bf16x8*)(Bg + k0 + 24);
    }
    __syncthreads();
    *(bf16x8*)(sAp)      = a0;
    *(bf16x8*)(sAp + 8)  = a1;
    *(bf16x8*)(sAp + 16) = a2;
    *(bf16x8*)(sAp + 24) = a3;
    *(bf16x8*)(sBp)      = b0;
    *(bf16x8*)(sBp + 8)  = b1;
    *(bf16x8*)(sBp + 16) = b2;
    *(bf16x8*)(sBp + 24) = b3;
    __syncthreads();
    #pragma unroll
    for (int ks = 0; ks < 2; ++ks) {
      bf16x8 af[4], bfr[4];
      #pragma unroll
      for (int i = 0; i < 4; ++i)
        af[i] = *(const bf16x8*)&sA[(wm + i * 16 + c) * LSTR2 + ks * 32 + q * 8];
      #pragma unroll
      for (int j = 0; j < 4; ++j)
        bfr[j] = *(const bf16x8*)&sB[(wn + j * 16 + c) * LSTR2 + ks * 32 + q * 8];
      #pragma unroll
      for (int i = 0; i < 4; ++i)
        #pragma unroll
        for (int j = 0; j < 4; ++j)
          acc[i][j] = __builtin_amdgcn_mfma_f32_16x16x32_bf16(af[i], bfr[j], acc[i][j], 0, 0, 0);
    }
  }
  #pragma unroll
  for (int i = 0; i < 4; ++i) {
    int m = bm + wm + i * 16 + q * 4;
    #pragma unroll
    for (int j = 0; j < 4; ++j) {
      int n = bn + wn + j * 16 + c;
      if (n < N) {
        #pragma unroll
        for (int r = 0; r < 4; ++r)
          C[(size_t)(m + r) * ldc + n] = f2bf(acc[i][j][r]);
      }
    }
  }
}

// fused out_proj + residual-add + next-layer rmsnorm. (unchanged, round-12)
__global__ __launch_bounds__(256) void outproj_norm(const ushort_t* __restrict__ yb,
    const ushort_t* __restrict__ zx, const ushort_t* __restrict__ Bw,
    const float* __restrict__ gw, float* __restrict__ resid,
    const float* __restrict__ wnext, ushort_t* __restrict__ hn) {
  __shared__ short sA[32 * LSTR];
  __shared__ short sB[256 * LSTR];
  __shared__ float swl[DI];
  __shared__ float swn[DM];
  __shared__ float rs[128];
  __shared__ float rs2[32 * 2];
  int tid = threadIdx.x;
  int bm = blockIdx.x * 32;
  int wave = tid >> 6, lane = tid & 63;
  int wm = (wave >> 1) * 16, wn = (wave & 1) * 128;
  int q = lane >> 4, c = lane & 15;
  swl[tid] = gw[tid];
  swl[tid + 256] = gw[tid + 256];
  swn[tid] = wnext[tid];

  f32x4 acc[8];
  #pragma unroll
  for (int j = 0; j < 8; ++j) acc[j] = (f32x4)0.f;

  int ar = tid >> 2, ak = (tid & 3) * 8;
  bool isa = tid < 128;
  const ushort_t* yrow = yb + (size_t)(bm + ar) * DI + ak;
  const ushort_t* zrow = zx + (size_t)(bm + ar) * DIPP + ak;
  const ushort_t* Bg = Bw + (size_t)tid * DI;
  float sumsq = 0.f;
  __syncthreads();

  for (int k0 = 0; k0 < DI; k0 += 32) {
    bf16x8 g8;
    if (isa) {
      bf16x8 y8 = *(const bf16x8*)(yrow + k0);
      bf16x8 z8 = *(const bf16x8*)(zrow + k0);
      #pragma unroll
      for (int e = 0; e < 8; ++e) {
        float zz = bf2f((ushort_t)z8[e]);
        float gg = bf2f((ushort_t)y8[e]) * (zz / (1.f + __expf(-zz)));
        sumsq += gg * gg;
        g8[e] = (short)f2bf(gg * swl[k0 + ak + e]);
      }
    }
    bf16x8 b0 = *(const bf16x8*)(Bg + k0);
    bf16x8 b1 = *(const bf16x8*)(Bg + k0 + 8);
    bf16x8 b2 = *(const bf16x8*)(Bg + k0 + 16);
    bf16x8 b3 = *(const bf16x8*)(Bg + k0 + 24);
    __syncthreads();
    if (isa) *(bf16x8*)&sA[ar * LSTR + ak] = g8;
    *(bf16x8*)&sB[tid * LSTR]      = b0;
    *(bf16x8*)&sB[tid * LSTR + 8]  = b1;
    *(bf16x8*)&sB[tid * LSTR + 16] = b2;
    *(bf16x8*)&sB[tid * LSTR + 24] = b3;
    __syncthreads();
    bf16x8 af = *(const bf16x8*)&sA[(wm + c) * LSTR + q * 8];
    #pragma unroll
    for (int j = 0; j < 8; ++j) {
      bf16x8 bfr = *(const bf16x8*)&sB[(wn + j * 16 + c) * LSTR + q * 8];
      acc[j] = __builtin_amdgcn_mfma_f32_16x16x32_bf16(af, bfr, acc[j], 0, 0, 0);
    }
  }
  if (isa) rs[tid] = sumsq;
  __syncthreads();

  float outv[8][4];
  float sq2[4];
  #pragma unroll
  for (int r = 0; r < 4; ++r) {
    int row = wm + q * 4 + r;
    float s1 = rsqrtf((rs[row * 4] + rs[row * 4 + 1] + rs[row * 4 + 2] + rs[row * 4 + 3])
                      * (1.f / DI) + 1e-5f);
    float sq = 0.f;
    #pragma unroll
    for (int j = 0; j < 8; ++j) {
      int col = wn + j * 16 + c;
      size_t ro = (size_t)(bm + row) * DM + col;
      float rn = resid[ro] + s1 * acc[j][r];
      resid[ro] = rn;
      outv[j][r] = rn;
      sq += rn * rn;
    }
    sq2[r] = sq;
  }
  #pragma unroll
  for (int r = 0; r < 4; ++r) {
    #pragma unroll
    for (int m = 1; m <= 8; m <<= 1) sq2[r] += __shfl_xor(sq2[r], m, 64);
  }
  if (c == 0) {
    #pragma unroll
    for (int r = 0; r < 4; ++r)
      rs2[(wm + q * 4 + r) * 2 + (wave & 1)] = sq2[r];
  }
  __syncthreads();
  #pragma unroll
  for (int r = 0; r < 4; ++r) {
    int row = wm + q * 4 + r;
    float s2 = rsqrtf((rs2[row * 2] + rs2[row * 2 + 1]) * (1.f / DM) + 1e-5f);
    #pragma unroll
    for (int j = 0; j < 8; ++j) {
      int col = wn + j * 16 + c;
      hn[(size_t)(bm + row) * DM + col] = f2bf(outv[j][r] * s2 * swn[col]);
    }
  }
}

// LDS-tiled conv(4)+bias+silu + fused U^T transpose. (unchanged, round-12)
__global__ __launch_bounds__(256) void conv_silu(const ushort_t* __restrict__ zx,
    const float* __restrict__ cw, const float* __restrict__ cb,
    const float* __restrict__ dtb, ushort_t* __restrict__ xo,
    ushort_t* __restrict__ Bo, ushort_t* __restrict__ Co, ushort_t* __restrict__ Ut) {
  __shared__ ushort_t tile[67 * 128];
  __shared__ ushort_t tt[128 * 72];
  __shared__ float sdt[64];
  int tid = threadIdx.x;
  int ct = blockIdx.x, tb_ = blockIdx.y, b = blockIdx.z;
  int c0 = ct * 128, l0 = tb_ * 64;
  size_t rowb = (size_t)b * LSEQ;
  bool isx = (ct < 4);
  for (int slot = tid; slot < 67 * 16; slot += 256) {
    int r = slot >> 4, gg = slot & 15;
    int l = l0 + r - 3;
    bf16x8 v = (bf16x8)(short)0;
    if (l >= 0) v = *(const bf16x8*)&zx[(rowb + l) * DIPP + DI + c0 + gg * 8];
    *(bf16x8*)&tile[r * 128 + gg * 8] = v;
  }
  if (isx && tid < 64) sdt[tid] = dtb[rowb + l0 + tid];
  int g = tid & 15, tq = tid >> 4;
  int cbase = c0 + g * 8;
  float w[4][8], bias[8];
  #pragma unroll
  for (int e = 0; e < 8; ++e) {
    float4 wv = *(const float4*)&cw[(cbase + e) * 4];
    w[0][e] = wv.x; w[1][e] = wv.y; w[2][e] = wv.z; w[3][e] = wv.w;
    bias[e] = cb[cbase + e];
  }
  __syncthreads();
  bf16x8 rows[7];
  #pragma unroll
  for (int r = 0; r < 7; ++r)
    rows[r] = *(const bf16x8*)&tile[(tq * 4 + r) * 128 + g * 8];
  #pragma unroll
  for (int it = 0; it < 4; ++it) {
    int t = tq * 4 + it;
    size_t tl = rowb + l0 + t;
    float dtv = isx ? sdt[t] : 0.f;
    bf16x8 o;
    #pragma unroll
    for (int e = 0; e < 8; ++e) {
      float s = bias[e]
              + w[0][e] * bf2f((ushort_t)rows[it][e])
              + w[1][e] * bf2f((ushort_t)rows[it + 1][e])
              + w[2][e] * bf2f((ushort_t)rows[it + 2][e])
              + w[3][e] * bf2f((ushort_t)rows[it + 3][e]);
      float v = s / (1.f + __expf(-s));
      o[e] = (short)f2bf(v);
      if (isx) tt[(g * 8 + e) * 72 + t] = f2bf(v * dtv);
    }
    if (isx) {
      *(bf16x8*)&xo[tl * DI + cbase] = o;
    } else if (g < 8) {
      *(bf16x8*)&Bo[tl * DS + (cbase - DI)] = o;
    } else {
      *(bf16x8*)&Co[tl * DS + (cbase - DI - DS)] = o;
    }
  }
  if (isx) {
    __syncthreads();
    #pragma unroll
    for (int pass = 0; pass < 4; ++pass) {
      int slot = pass * 256 + tid;
      int op = slot >> 3, sg = slot & 7;
      bf16x8 v = *(const bf16x8*)&tt[op * 72 + sg * 8];
      *(bf16x8*)&Ut[((size_t)b * DI + c0 + op) * LSEQ + l0 + sg * 8] = v;
    }
  }
}

// dt softplus + per-chunk prefix sum. (unchanged, round-12)
__global__ __launch_bounds__(256) void csum_k(const ushort_t* __restrict__ zx,
    const float* __restrict__ dtbias, float* __restrict__ dtb, float* __restrict__ csumb) {
  int tid = threadIdx.x;
  int wave = tid >> 6, lane = tid & 63;
  int cg = blockIdx.x * 4 + wave;
  int b = cg >> 4, ch = cg & 15;
  size_t base = (size_t)b * LSEQ + ch * CL;
  float bias = dtbias[0];
  float x0 = bf2f(zx[(base + 2 * lane) * DIPP + (DIP - 1)]) + bias;
  float x1 = bf2f(zx[(base + 2 * lane + 1) * DIPP + (DIP - 1)]) + bias;
  float d0 = (x0 > 20.f) ? x0 : log1pf(__expf(x0));
  float d1 = (x1 > 20.f) ? x1 : log1pf(__expf(x1));
  dtb[base + 2 * lane] = d0;
  dtb[base + 2 * lane + 1] = d1;
  float p = d0 + d1;
  #pragma unroll
  for (int off = 1; off < 64; off <<= 1) {
    float t = __shfl_up(p, off, 64);
    if (lane >= off) p += t;
  }
  csumb[base + 2 * lane]     = p - d1;
  csumb[base + 2 * lane + 1] = p;
}

// state GEMM (unchanged, round-12 / r9 version)
__global__ __launch_bounds__(256) void state_gemm(const ushort_t* __restrict__ Bb,
    const ushort_t* __restrict__ Ut, const float* __restrict__ csumb,
    const float* __restrict__ alog, float* __restrict__ hst) {
  __shared__ short sW[64 * 144];
  __shared__ short sX[128 * 40];
  __shared__ float scs[128];
  int tid = threadIdx.x;
  int ph = blockIdx.x, ch = blockIdx.y, b = blockIdx.z;
  int bc = b * NC + ch;
  size_t tb = (size_t)b * LSEQ + ch * CL;
  float Aval = -expf(alog[0]);
  if (tid < 128) scs[tid] = csumb[tb + tid];
  __syncthreads();
  float Stot = scs[127];
  {
    int s = tid >> 1, noff = (tid & 1) * 32;
    float scale = __expf(Aval * (Stot - scs[s]));
    #pragma unroll
    for (int blk = 0; blk < 4; ++blk) {
      bf16x8 v = *(const bf16x8*)&Bb[(tb + s) * DS + noff + blk * 8];
      #pragma unroll
      for (int e = 0; e < 8; ++e)
        sW[(noff + blk * 8 + e) * 144 + s] = (short)f2bf(bf2f((ushort_t)v[e]) * scale);
    }
  }
  int wave = tid >> 6, lane = tid & 63;
  int wn = (wave >> 1) * 32, wp = (wave & 1) * 64;
  int q = lane >> 4, c = lane & 15;
  f32x4 acc[2][4];
  #pragma unroll
  for (int i = 0; i < 2; ++i)
    #pragma unroll
    for (int j = 0; j < 4; ++j) acc[i][j] = (f32x4)0.f;

  for (int ks = 0; ks < 4; ++ks) {
    __syncthreads();
    {
      int r = tid >> 1, off = (tid & 1) * 16;
      size_t ua = ((size_t)b * DI + ph * 128 + r) * LSEQ + ch * CL + ks * 32 + off;
      bf16x8 u0 = *(const bf16x8*)&Ut[ua];
      bf16x8 u1 = *(const bf16x8*)&Ut[ua + 8];
      *(bf16x8*)&sX[r * 40 + off]     = u0;
      *(bf16x8*)&sX[r * 40 + off + 8] = u1;
    }
    __syncthreads();
    bf16x8 af[2], bfr[4];
    #pragma unroll
    for (int i = 0; i < 2; ++i)
      af[i] = *(const bf16x8*)&sW[(wn + i * 16 + c) * 144 + ks * 32 + q * 8];
    #pragma unroll
    for (int j = 0; j < 4; ++j)
      bfr[j] = *(const bf16x8*)&sX[(wp + j * 16 + c) * 40 + q * 8];
    #pragma unroll
    for (int i = 0; i < 2; ++i)
      #pragma unroll
      for (int j = 0; j < 4; ++j)
        acc[i][j] = __builtin_amdgcn_mfma_f32_16x16x32_bf16(af[i], bfr[j], acc[i][j], 0, 0, 0);
  }
  #pragma unroll
  for (int i = 0; i < 2; ++i) {
    int n = wn + i * 16 + q * 4;
    #pragma unroll
    for (int j = 0; j < 4; ++j) {
      int pg = ph * 128 + wp + j * 16 + c;
      #pragma unroll
      for (int r = 0; r < 4; ++r)
        hst[((size_t)bc * DS + n + r) * DI + pg] = acc[i][j][r];
    }
  }
}

// combine (unchanged, round-12)
__global__ __launch_bounds__(256) void combine2(const float* __restrict__ hst,
    const float* __restrict__ csumb, const float* __restrict__ alog,
    ushort_t* __restrict__ hin) {
  __shared__ ushort_t ts[64 * 17];
  int tid = threadIdx.x;
  int pt = blockIdx.x, nt = blockIdx.y, b = blockIdx.z;
  int p0 = pt * 64, n0 = nt * 16;
  int pl = tid & 63, ng = tid >> 6;
  float Aval = -expf(alog[0]);
  float h[4];
  #pragma unroll
  for (int i = 0; i < 4; ++i) h[i] = 0.f;
  for (int c = 0; c < NC; ++c) {
    int bc = b * NC + c;
    #pragma unroll
    for (int i = 0; i < 4; ++i)
      ts[pl * 17 + ng * 4 + i] = f2bf(h[i]);
    __syncthreads();
    {
      int on = tid & 15;
      #pragma unroll
      for (int pass = 0; pass < 4; ++pass) {
        int op = (tid >> 4) + pass * 16;
        hin[((size_t)bc * DI + p0 + op) * DS + n0 + on] = ts[op * 17 + on];
      }
    }
    __syncthreads();
    float Sc = csumb[(size_t)b * LSEQ + c * CL + CL - 1];
    float dec = __expf(Aval * Sc);
    #pragma unroll
    for (int i = 0; i < 4; ++i) {
      float loc = hst[((size_t)bc * DS + n0 + ng * 4 + i) * DI + p0 + pl];
      h[i] = h[i] * dec + loc;
    }
  }
}

// y GEMM — LDS diet: only sM + sU(narrow) staged (45.8 KB -> 3 blocks/CU).
// B/C fragments direct from global (L2-resident, shared across the 4 p-tile
// blocks of each chunk); Ut/hin still LDS-staged (r11 showed direct Ut is bad).
// Packed u32 sM writes. Chat built in-register.
__global__ __launch_bounds__(256) void y_gemm(const ushort_t* __restrict__ Bb,
    const ushort_t* __restrict__ Cb, const ushort_t* __restrict__ Ut,
    const ushort_t* __restrict__ hin, const float* __restrict__ csumb,
    const float* __restrict__ alog, const float* __restrict__ dpar,
    const ushort_t* __restrict__ xb, ushort_t* __restrict__ y) {
  __shared__ short sM[128 * 136];   // 34.8 KB
  __shared__ short sU[128 * 40];    // 10.2 KB
  __shared__ float scs[128];
  int tid = threadIdx.x;
  int ph = blockIdx.x, ch = blockIdx.y, b = blockIdx.z;
  int bc = b * NC + ch;
  size_t tb = (size_t)b * LSEQ + ch * CL;
  float Aval = -expf(alog[0]);
  float dp = dpar[0];
  int wave = tid >> 6, lane = tid & 63;
  int q = lane >> 4, c = lane & 15;

  if (tid < 128) scs[tid] = csumb[tb + tid];
  __syncthreads();

  // phase 1: G = C @ B^T (128t x 128s, K=64), operands direct from global.
  // Wave 1's quadrant (t 0-63, s 64-127) is fully causal-masked: zero-fill.
  {
    int wm = (wave >> 1) * 64, wss = (wave & 1) * 64;
    if (wave == 1) {
      #pragma unroll
      for (int it = 0; it < 32; ++it) {
        int idx = it * 64 + lane;       // 2048 u32 slots = 64 rows x 64 shorts
        int row = idx >> 5;
        int col = (idx & 31) * 2;
        *(unsigned int*)&sM[row * 136 + 64 + col] = 0u;
      }
    } else {
      f32x4 g[4][4];
      #pragma unroll
      for (int i = 0; i < 4; ++i)
        #pragma unroll
        for (int j = 0; j < 4; ++j) g[i][j] = (f32x4)0.f;
      #pragma unroll
      for (int k0 = 0; k0 < 64; k0 += 32) {
        bf16x8 af[4], bfr[4];
        #pragma unroll
        for (int i = 0; i < 4; ++i)
          af[i] = *(const bf16x8*)&Cb[(tb + wm + i * 16 + c) * DS + k0 + q * 8];
        #pragma unroll
        for (int j = 0; j < 4; ++j)
          bfr[j] = *(const bf16x8*)&Bb[(tb + wss + j * 16 + c) * DS + k0 + q * 8];
        #pragma unroll
        for (int i = 0; i < 4; ++i)
          #pragma unroll
          for (int j = 0; j < 4; ++j)
            g[i][j] = __builtin_amdgcn_mfma_f32_16x16x32_bf16(af[i], bfr[j], g[i][j], 0, 0, 0);
      }
      // mask + decay; pack lane pairs into u32 stores (even lanes write)
      #pragma unroll
      for (int i = 0; i < 4; ++i) {
        #pragma unroll
        for (int r = 0; r < 4; ++r) {
          int t = wm + i * 16 + q * 4 + r;
          float ct = scs[t];
          #pragma unroll
          for (int j = 0; j < 4; ++j) {
            int s = wss + j * 16 + c;
            float v = g[i][j][r];
            float m = (s <= t) ? v * __expf(Aval * (ct - scs[s])) : 0.f;
            unsigned int mb = (unsigned int)f2bf(m);
            unsigned int partner = __shfl_xor(mb, 1, 64);
            if ((c & 1) == 0)
              *(unsigned int*)&sM[t * 136 + s] = mb | (partner << 16);
          }
        }
      }
    }
  }

  // phase 2: Y (128t x 128p) = M @ U + Chat @ Hin
  int wm2 = (wave >> 1) * 64, wp = (wave & 1) * 64;
  f32x4 acc[4][4];
  #pragma unroll
  for (int i = 0; i < 4; ++i)
    #pragma unroll
    for (int j = 0; j < 4; ++j) acc[i][j] = (f32x4)0.f;

  for (int ks = 0; ks < 4; ++ks) {
    __syncthreads();   // (first iter also covers sM writes)
    {
      int r = tid >> 1, off = (tid & 1) * 16;
      size_t ua = ((size_t)b * DI + ph * 128 + r) * LSEQ + ch * CL + ks * 32 + off;
      bf16x8 u0 = *(const bf16x8*)&Ut[ua];
      bf16x8 u1 = *(const bf16x8*)&Ut[ua + 8];
      *(bf16x8*)&sU[r * 40 + off]     = u0;
      *(bf16x8*)&sU[r * 40 + off + 8] = u1;
    }
    __syncthreads();
    if (!(wm2 == 0 && ks >= 2)) {   // M upper-right quadrant is zero
      bf16x8 af[4], bfr[4];
      #pragma unroll
      for (int i = 0; i < 4; ++i)
        af[i] = *(const bf16x8*)&sM[(wm2 + i * 16 + c) * 136 + ks * 32 + q * 8];
      #pragma unroll
      for (int j = 0; j < 4; ++j)
        bfr[j] = *(const bf16x8*)&sU[(wp + j * 16 + c) * 40 + q * 8];
      #pragma unroll
      for (int i = 0; i < 4; ++i)
        #pragma unroll
        for (int j = 0; j < 4; ++j)
          acc[i][j] = __builtin_amdgcn_mfma_f32_16x16x32_bf16(af[i], bfr[j], acc[i][j], 0, 0, 0);
    }
  }

  // Chat @ Hin: Chat rows in-register (per-lane row scale); hin staged in sU
  float rscale[4];
  #pragma unroll
  for (int i = 0; i < 4; ++i)
    rscale[i] = __expf(Aval * scs[wm2 + i * 16 + c]);
  for (int ks2 = 0; ks2 < 2; ++ks2) {
    __syncthreads();
    {
      int r = tid >> 1, off = (tid & 1) * 16;
      size_t ha = ((size_t)bc * DI + ph * 128 + r) * DS + ks2 * 32 + off;
      bf16x8 h0 = *(const bf16x8*)&hin[ha];
      bf16x8 h1 = *(const bf16x8*)&hin[ha + 8];
      *(bf16x8*)&sU[r * 40 + off]     = h0;
      *(bf16x8*)&sU[r * 40 + off + 8] = h1;
    }
    __syncthreads();
    bf16x8 af[4], bfr[4];
    #pragma unroll
    for (int j = 0; j < 4; ++j)
      bfr[j] = *(const bf16x8*)&sU[(wp + j * 16 + c) * 40 + q * 8];
    #pragma unroll
    for (int i = 0; i < 4; ++i) {
      bf16x8 cf = *(const bf16x8*)&Cb[(tb + wm2 + i * 16 + c) * DS + ks2 * 32 + q * 8];
      #pragma unroll
      for (int e = 0; e < 8; ++e)
        af[i][e] = (short)f2bf(bf2f((ushort_t)cf[e]) * rscale[i]);
    }
    #pragma unroll
    for (int i = 0; i < 4; ++i)
      #pragma unroll
      for (int j = 0; j < 4; ++j)
        acc[i][j] = __builtin_amdgcn_mfma_f32_16x16x32_bf16(af[i], bfr[j], acc[i][j], 0, 0, 0);
  }

  #pragma unroll
  for (int i = 0; i < 4; ++i) {
    #pragma unroll
    for (int r = 0; r < 4; ++r) {
      int t = wm2 + i * 16 + q * 4 + r;
      size_t row = (tb + t) * DI;
      #pragma unroll
      for (int j = 0; j < 4; ++j) {
        int pg = ph * 128 + wp + j * 16 + c;
        y[row + pg] = f2bf(acc[i][j][r] + dp * bf2f(xb[row + pg]));
      }
    }
  }
}

// last token only: logits = hn_final @ embed[:100].T
__global__ __launch_bounds__(256) void finalize(const ushort_t* __restrict__ hn,
    const float* __restrict__ embed, float* __restrict__ out) {
  int b = blockIdx.x, tid = threadIdx.x;
  __shared__ float fin[DM];
  size_t off = ((size_t)b * LSEQ + (LSEQ - 1)) * DM;
  fin[tid] = bf2f(hn[off + tid]);
  __syncthreads();
  if (tid < VOC) {
    float acc = 0.f;
    #pragma unroll 8
    for (int d = 0; d < DM; ++d) acc += fin[d] * embed[(size_t)tid * DM + d];
    out[b * VOC + tid] = acc;
  }
}

extern "C" void kernel_launch(void* const* d_in, const int* in_sizes, int n_in,
                              void* d_out, int out_size, void* d_ws, size_t ws_size,
                              hipStream_t stream) {
  const int*   ids   = (const int*)d_in[0];
  const float* embed = (const float*)d_in[1];
  const float* ipw   = (const float*)d_in[2];
  const float* cw    = (const float*)d_in[3];
  const float* cb    = (const float*)d_in[4];
  const float* dtbias= (const float*)d_in[5];
  const float* alog  = (const float*)d_in[6];
  const float* dpar  = (const float*)d_in[7];
  const float* ngw   = (const float*)d_in[8];
  const float* opw   = (const float*)d_in[9];
  const float* bnw   = (const float*)d_in[10];
  const float* nfw   = (const float*)d_in[11];
  float* out = (float*)d_out;

  // workspace layout (~140 MB)
  char* p = (char*)d_ws;
  float* resid = (float*)p;            p += (size_t)TKN * DM * 4;
  ushort_t* hn = (ushort_t*)p;         p += (size_t)TKN * DM * 2;
  ushort_t* zx = (ushort_t*)p;         p += (size_t)TKN * DIPP * 2;
  float* dtb   = (float*)p;            p += (size_t)TKN * 4;
  float* csumb = (float*)p;            p += (size_t)TKN * 4;
  ushort_t* xb = (ushort_t*)p;         p += (size_t)TKN * DI * 2;
  ushort_t* yb = (ushort_t*)p;         p += (size_t)TKN * DI * 2;
  ushort_t* Bb = (ushort_t*)p;         p += (size_t)TKN * DS * 2;
  ushort_t* Cb = (ushort_t*)p;         p += (size_t)TKN * DS * 2;
  ushort_t* Ut = (ushort_t*)p;         p += (size_t)TKN * DI * 2;
  ushort_t* hin= (ushort_t*)p;         p += (size_t)NB * NC * DI * DS * 2;
  ushort_t* wbi= (ushort_t*)p;         p += (size_t)NL * DIP * DM * 2;
  ushort_t* wbo= (ushort_t*)p;         p += (size_t)NL * DM * DI * 2;
  // hst (fp32) aliases yb (bf16): consumed by combine2 before y_gemm writes yb
  float* hst = (float*)yb;

  convert_w<<<(NL * DIP * DM + NL * DM * DI + 1023) / 1024, 256, 0, stream>>>(
      ipw, opw, wbi, wbo);
  embed_rmsnorm<<<TKN / 4, 256, 0, stream>>>(resid, hn, bnw, ids, embed);

  for (int i = 0; i < NL; ++i) {
    gemm_nt_bf16<<<dim3((DIP + 127) / 128, TKN / 128), 256, 0, stream>>>(
        hn, wbi + (size_t)i * DIP * DM, zx, DIP, DM, DIPP);
    csum_k<<<32, 256, 0, stream>>>(zx, dtbias + i, dtb, csumb);
    conv_silu<<<dim3(CDIM / 128, LSEQ / 64, NB), 256, 0, stream>>>(
        zx, cw + (size_t)i * CDIM * 4, cb + (size_t)i * CDIM, dtb, xb, Bb, Cb, Ut);
    state_gemm<<<dim3(4, NC, NB), 256, 0, stream>>>(Bb, Ut, csumb, alog + i, hst);
    combine2<<<dim3(DI / 64, 4, NB), 256, 0, stream>>>(hst, csumb, alog + i, hin);
    y_gemm<<<dim3(4, NC, NB), 256, 0, stream>>>(Bb, Cb, Ut, hin, csumb, alog + i,
                                                dpar + i, xb, yb);
    const float* wnext = (i < NL - 1) ? (bnw + (size_t)(i + 1) * DM) : nfw;
    outproj_norm<<<TKN / 32, 256, 0, stream>>>(
        yb, zx, wbo + (size_t)i * DM * DI, ngw + (size_t)i * DI, resid, wnext, hn);
  }

  finalize<<<NB, 256, 0, stream>>>(hn, embed, out);
}

// Round 14
// 569.099 us; speedup vs baseline: 1.0151x; 1.0151x over previous
//
#include <hip/hip_runtime.h>
#include <math.h>

// ---- problem constants ----
#define NB    8        // batch
#define LSEQ  2048     // seq len
#define TKN   16384    // NB*LSEQ tokens
#define DM    256      // d_model
#define DI    512      // d_inner
#define DS    64       // d_state
#define DIP   1153     // 2*DI + 2*DS + 1
#define DIPP  1160     // padded row stride for zx (bf16)
#define CDIM  640      // DI + 2*DS
#define NL    4
#define NC    16       // scan chunks
#define CL    128      // LSEQ/NC
#define VOC   100

typedef short bf16x8 __attribute__((ext_vector_type(8)));
typedef short bf16x4 __attribute__((ext_vector_type(4)));
typedef float f32x4  __attribute__((ext_vector_type(4)));
typedef unsigned short ushort_t;

__device__ __forceinline__ unsigned short f2bf(float f) {
  unsigned int u = __float_as_uint(f);
  unsigned int r = u + 0x7FFFu + ((u >> 16) & 1u);   // RNE
  return (unsigned short)(r >> 16);
}
__device__ __forceinline__ float bf2f(unsigned short u) {
  return __uint_as_float(((unsigned int)u) << 16);
}

// convert fp32 weights -> bf16 once per call
__global__ __launch_bounds__(256) void convert_w(const float* __restrict__ ipw,
    const float* __restrict__ opw, ushort_t* __restrict__ wbi, ushort_t* __restrict__ wbo) {
  const int n1 = NL * DIP * DM;
  const int n2 = NL * DM * DI;
  int i4 = (blockIdx.x * 256 + threadIdx.x) * 4;
  if (i4 < n1) {
    float4 v = *(const float4*)(ipw + i4);
    bf16x4 o; o[0] = (short)f2bf(v.x); o[1] = (short)f2bf(v.y);
    o[2] = (short)f2bf(v.z); o[3] = (short)f2bf(v.w);
    *(bf16x4*)(wbi + i4) = o;
  } else {
    int j = i4 - n1;
    if (j < n2) {
      float4 v = *(const float4*)(opw + j);
      bf16x4 o; o[0] = (short)f2bf(v.x); o[1] = (short)f2bf(v.y);
      o[2] = (short)f2bf(v.z); o[3] = (short)f2bf(v.w);
      *(bf16x4*)(wbo + j) = o;
    }
  }
}

// layer 0 only: resid = embed gather; hn = bf16(rmsnorm(resid)*w). One wave/token.
__global__ __launch_bounds__(256) void embed_rmsnorm(float* __restrict__ resid,
    ushort_t* __restrict__ hn, const float* __restrict__ w,
    const int* __restrict__ ids, const float* __restrict__ embed) {
  int wave = threadIdx.x >> 6, lane = threadIdx.x & 63;
  int t = blockIdx.x * 4 + wave;
  size_t o = (size_t)t * DM + lane * 4;
  int id = ids[t];
  float4 r4 = *(const float4*)&embed[(size_t)id * DM + lane * 4];
  *(float4*)&resid[o] = r4;
  float ss = r4.x * r4.x + r4.y * r4.y + r4.z * r4.z + r4.w * r4.w;
  #pragma unroll
  for (int m = 32; m >= 1; m >>= 1) ss += __shfl_xor(ss, m, 64);
  float sc = rsqrtf(ss * (1.f / DM) + 1e-5f);
  float4 w4 = *(const float4*)&w[lane * 4];
  bf16x4 o4;
  o4[0] = (short)f2bf(r4.x * sc * w4.x);
  o4[1] = (short)f2bf(r4.y * sc * w4.y);
  o4[2] = (short)f2bf(r4.z * sc * w4.z);
  o4[3] = (short)f2bf(r4.w * sc * w4.w);
  *(bf16x4*)&hn[o] = o4;
}

// ---------------- bf16 MFMA GEMM (A bf16, B bf16), BK=64 ----------------
#define LSTR  40
#define LSTR2 72
__global__ __launch_bounds__(256) void gemm_nt_bf16(const ushort_t* __restrict__ A,
    const ushort_t* __restrict__ Bw, ushort_t* __restrict__ C, int N, int K, int ldc) {
  __shared__ short sA[128 * LSTR2];
  __shared__ short sB[128 * LSTR2];
  int tid = threadIdx.x;
  int bn = blockIdx.x * 128;
  int bm = blockIdx.y * 128;
  int wave = tid >> 6, lane = tid & 63;
  int wm = (wave >> 1) * 64, wn = (wave & 1) * 64;
  int q = lane >> 4, c = lane & 15;

  f32x4 acc[4][4];
  #pragma unroll
  for (int i = 0; i < 4; ++i)
    #pragma unroll
    for (int j = 0; j < 4; ++j) acc[i][j] = (f32x4)0.f;

  int sr = tid >> 1;
  int sc = (tid & 1) * 32;
  const ushort_t* Ag = A + (size_t)(bm + sr) * K + sc;
  const ushort_t* Bg = Bw + (size_t)(bn + sr) * K + sc;
  bool bok = (bn + sr) < N;
  short* sAp = &sA[sr * LSTR2 + sc];
  short* sBp = &sB[sr * LSTR2 + sc];

  for (int k0 = 0; k0 < K; k0 += 64) {
    bf16x8 a0 = *(const bf16x8*)(Ag + k0);
    bf16x8 a1 = *(const bf16x8*)(Ag + k0 + 8);
    bf16x8 a2 = *(const bf16x8*)(Ag + k0 + 16);
    bf16x8 a3 = *(const bf16x8*)(Ag + k0 + 24);
    bf16x8 b0 = (bf16x8)(short)0, b1 = (bf16x8)(short)0;
    bf16x8 b2 = (bf16x8)(short)0, b3 = (bf16x8)(short)0;
    if (bok) {
      b0 = *(const bf16x8*)(Bg + k0);
      b1 = *(const bf16x8*)(Bg + k0 + 8);
      b2 = *(const bf16x8*)(Bg + k0 + 16);
      b3 = *(const bf16x8*)(Bg + k0 + 24);
    }
    __syncthreads();
    *(bf16x8*)(sAp)      = a0;
    *(bf16x8*)(sAp + 8)  = a1;
    *(bf16x8*)(sAp + 16) = a2;
    *(bf16x8*)(sAp + 24) = a3;
    *(bf16x8*)(sBp)      = b0;
    *(bf16x8*)(sBp + 8)  = b1;
    *(bf16x8*)(sBp + 16) = b2;
    *(bf16x8*)(sBp + 24) = b3;
    __syncthreads();
    #pragma unroll
    for (int ks = 0; ks < 2; ++ks) {
      bf16x8 af[4], bfr[4];
      #pragma unroll
      for (int i = 0; i < 4; ++i)
        af[i] = *(const bf16x8*)&sA[(wm + i * 16 + c) * LSTR2 + ks * 32 + q * 8];
      #pragma unroll
      for (int j = 0; j < 4; ++j)
        bfr[j] = *(const bf16x8*)&sB[(wn + j * 16 + c) * LSTR2 + ks * 32 + q * 8];
      #pragma unroll
      for (int i = 0; i < 4; ++i)
        #pragma unroll
        for (int j = 0; j < 4; ++j)
          acc[i][j] = __builtin_amdgcn_mfma_f32_16x16x32_bf16(af[i], bfr[j], acc[i][j], 0, 0, 0);
    }
  }
  #pragma unroll
  for (int i = 0; i < 4; ++i) {
    int m = bm + wm + i * 16 + q * 4;
    #pragma unroll
    for (int j = 0; j < 4; ++j) {
      int n = bn + wn + j * 16 + c;
      if (n < N) {
        #pragma unroll
        for (int r = 0; r < 4; ++r)
          C[(size_t)(m + r) * ldc + n] = f2bf(acc[i][j][r]);
      }
    }
  }
}

// fused out_proj + residual-add + next-layer rmsnorm. (unchanged, round-12)
__global__ __launch_bounds__(256) void outproj_norm(const ushort_t* __restrict__ yb,
    const ushort_t* __restrict__ zx, const ushort_t* __restrict__ Bw,
    const float* __restrict__ gw, float* __restrict__ resid,
    const float* __restrict__ wnext, ushort_t* __restrict__ hn) {
  __shared__ short sA[32 * LSTR];
  __shared__ short sB[256 * LSTR];
  __shared__ float swl[DI];
  __shared__ float swn[DM];
  __shared__ float rs[128];
  __shared__ float rs2[32 * 2];
  int tid = threadIdx.x;
  int bm = blockIdx.x * 32;
  int wave = tid >> 6, lane = tid & 63;
  int wm = (wave >> 1) * 16, wn = (wave & 1) * 128;
  int q = lane >> 4, c = lane & 15;
  swl[tid] = gw[tid];
  swl[tid + 256] = gw[tid + 256];
  swn[tid] = wnext[tid];

  f32x4 acc[8];
  #pragma unroll
  for (int j = 0; j < 8; ++j) acc[j] = (f32x4)0.f;

  int ar = tid >> 2, ak = (tid & 3) * 8;
  bool isa = tid < 128;
  const ushort_t* yrow = yb + (size_t)(bm + ar) * DI + ak;
  const ushort_t* zrow = zx + (size_t)(bm + ar) * DIPP + ak;
  const ushort_t* Bg = Bw + (size_t)tid * DI;
  float sumsq = 0.f;
  __syncthreads();

  for (int k0 = 0; k0 < DI; k0 += 32) {
    bf16x8 g8;
    if (isa) {
      bf16x8 y8 = *(const bf16x8*)(yrow + k0);
      bf16x8 z8 = *(const bf16x8*)(zrow + k0);
      #pragma unroll
      for (int e = 0; e < 8; ++e) {
        float zz = bf2f((ushort_t)z8[e]);
        float gg = bf2f((ushort_t)y8[e]) * (zz / (1.f + __expf(-zz)));
        sumsq += gg * gg;
        g8[e] = (short)f2bf(gg * swl[k0 + ak + e]);
      }
    }
    bf16x8 b0 = *(const bf16x8*)(Bg + k0);
    bf16x8 b1 = *(const bf16x8*)(Bg + k0 + 8);
    bf16x8 b2 = *(const bf16x8*)(Bg + k0 + 16);
    bf16x8 b3 = *(const bf16x8*)(Bg + k0 + 24);
    __syncthreads();
    if (isa) *(bf16x8*)&sA[ar * LSTR + ak] = g8;
    *(bf16x8*)&sB[tid * LSTR]      = b0;
    *(bf16x8*)&sB[tid * LSTR + 8]  = b1;
    *(bf16x8*)&sB[tid * LSTR + 16] = b2;
    *(bf16x8*)&sB[tid * LSTR + 24] = b3;
    __syncthreads();
    bf16x8 af = *(const bf16x8*)&sA[(wm + c) * LSTR + q * 8];
    #pragma unroll
    for (int j = 0; j < 8; ++j) {
      bf16x8 bfr = *(const bf16x8*)&sB[(wn + j * 16 + c) * LSTR + q * 8];
      acc[j] = __builtin_amdgcn_mfma_f32_16x16x32_bf16(af, bfr, acc[j], 0, 0, 0);
    }
  }
  if (isa) rs[tid] = sumsq;
  __syncthreads();

  float outv[8][4];
  float sq2[4];
  #pragma unroll
  for (int r = 0; r < 4; ++r) {
    int row = wm + q * 4 + r;
    float s1 = rsqrtf((rs[row * 4] + rs[row * 4 + 1] + rs[row * 4 + 2] + rs[row * 4 + 3])
                      * (1.f / DI) + 1e-5f);
    float sq = 0.f;
    #pragma unroll
    for (int j = 0; j < 8; ++j) {
      int col = wn + j * 16 + c;
      size_t ro = (size_t)(bm + row) * DM + col;
      float rn = resid[ro] + s1 * acc[j][r];
      resid[ro] = rn;
      outv[j][r] = rn;
      sq += rn * rn;
    }
    sq2[r] = sq;
  }
  #pragma unroll
  for (int r = 0; r < 4; ++r) {
    #pragma unroll
    for (int m = 1; m <= 8; m <<= 1) sq2[r] += __shfl_xor(sq2[r], m, 64);
  }
  if (c == 0) {
    #pragma unroll
    for (int r = 0; r < 4; ++r)
      rs2[(wm + q * 4 + r) * 2 + (wave & 1)] = sq2[r];
  }
  __syncthreads();
  #pragma unroll
  for (int r = 0; r < 4; ++r) {
    int row = wm + q * 4 + r;
    float s2 = rsqrtf((rs2[row * 2] + rs2[row * 2 + 1]) * (1.f / DM) + 1e-5f);
    #pragma unroll
    for (int j = 0; j < 8; ++j) {
      int col = wn + j * 16 + c;
      hn[(size_t)(bm + row) * DM + col] = f2bf(outv[j][r] * s2 * swn[col]);
    }
  }
}

// LDS-tiled conv(4)+bias+silu + fused U^T transpose. (unchanged, round-12)
__global__ __launch_bounds__(256) void conv_silu(const ushort_t* __restrict__ zx,
    const float* __restrict__ cw, const float* __restrict__ cb,
    const float* __restrict__ dtb, ushort_t* __restrict__ xo,
    ushort_t* __restrict__ Bo, ushort_t* __restrict__ Co, ushort_t* __restrict__ Ut) {
  __shared__ ushort_t tile[67 * 128];
  __shared__ ushort_t tt[128 * 72];
  __shared__ float sdt[64];
  int tid = threadIdx.x;
  int ct = blockIdx.x, tb_ = blockIdx.y, b = blockIdx.z;
  int c0 = ct * 128, l0 = tb_ * 64;
  size_t rowb = (size_t)b * LSEQ;
  bool isx = (ct < 4);
  for (int slot = tid; slot < 67 * 16; slot += 256) {
    int r = slot >> 4, gg = slot & 15;
    int l = l0 + r - 3;
    bf16x8 v = (bf16x8)(short)0;
    if (l >= 0) v = *(const bf16x8*)&zx[(rowb + l) * DIPP + DI + c0 + gg * 8];
    *(bf16x8*)&tile[r * 128 + gg * 8] = v;
  }
  if (isx && tid < 64) sdt[tid] = dtb[rowb + l0 + tid];
  int g = tid & 15, tq = tid >> 4;
  int cbase = c0 + g * 8;
  float w[4][8], bias[8];
  #pragma unroll
  for (int e = 0; e < 8; ++e) {
    float4 wv = *(const float4*)&cw[(cbase + e) * 4];
    w[0][e] = wv.x; w[1][e] = wv.y; w[2][e] = wv.z; w[3][e] = wv.w;
    bias[e] = cb[cbase + e];
  }
  __syncthreads();
  bf16x8 rows[7];
  #pragma unroll
  for (int r = 0; r < 7; ++r)
    rows[r] = *(const bf16x8*)&tile[(tq * 4 + r) * 128 + g * 8];
  #pragma unroll
  for (int it = 0; it < 4; ++it) {
    int t = tq * 4 + it;
    size_t tl = rowb + l0 + t;
    float dtv = isx ? sdt[t] : 0.f;
    bf16x8 o;
    #pragma unroll
    for (int e = 0; e < 8; ++e) {
      float s = bias[e]
              + w[0][e] * bf2f((ushort_t)rows[it][e])
              + w[1][e] * bf2f((ushort_t)rows[it + 1][e])
              + w[2][e] * bf2f((ushort_t)rows[it + 2][e])
              + w[3][e] * bf2f((ushort_t)rows[it + 3][e]);
      float v = s / (1.f + __expf(-s));
      o[e] = (short)f2bf(v);
      if (isx) tt[(g * 8 + e) * 72 + t] = f2bf(v * dtv);
    }
    if (isx) {
      *(bf16x8*)&xo[tl * DI + cbase] = o;
    } else if (g < 8) {
      *(bf16x8*)&Bo[tl * DS + (cbase - DI)] = o;
    } else {
      *(bf16x8*)&Co[tl * DS + (cbase - DI - DS)] = o;
    }
  }
  if (isx) {
    __syncthreads();
    #pragma unroll
    for (int pass = 0; pass < 4; ++pass) {
      int slot = pass * 256 + tid;
      int op = slot >> 3, sg = slot & 7;
      bf16x8 v = *(const bf16x8*)&tt[op * 72 + sg * 8];
      *(bf16x8*)&Ut[((size_t)b * DI + c0 + op) * LSEQ + l0 + sg * 8] = v;
    }
  }
}

// dt softplus + per-chunk prefix sum. (unchanged, round-12)
__global__ __launch_bounds__(256) void csum_k(const ushort_t* __restrict__ zx,
    const float* __restrict__ dtbias, float* __restrict__ dtb, float* __restrict__ csumb) {
  int tid = threadIdx.x;
  int wave = tid >> 6, lane = tid & 63;
  int cg = blockIdx.x * 4 + wave;
  int b = cg >> 4, ch = cg & 15;
  size_t base = (size_t)b * LSEQ + ch * CL;
  float bias = dtbias[0];
  float x0 = bf2f(zx[(base + 2 * lane) * DIPP + (DIP - 1)]) + bias;
  float x1 = bf2f(zx[(base + 2 * lane + 1) * DIPP + (DIP - 1)]) + bias;
  float d0 = (x0 > 20.f) ? x0 : log1pf(__expf(x0));
  float d1 = (x1 > 20.f) ? x1 : log1pf(__expf(x1));
  dtb[base + 2 * lane] = d0;
  dtb[base + 2 * lane + 1] = d1;
  float p = d0 + d1;
  #pragma unroll
  for (int off = 1; off < 64; off <<= 1) {
    float t = __shfl_up(p, off, 64);
    if (lane >= off) p += t;
  }
  csumb[base + 2 * lane]     = p - d1;
  csumb[base + 2 * lane + 1] = p;
}

// state GEMM (unchanged, round-12 / r9 version)
__global__ __launch_bounds__(256) void state_gemm(const ushort_t* __restrict__ Bb,
    const ushort_t* __restrict__ Ut, const float* __restrict__ csumb,
    const float* __restrict__ alog, float* __restrict__ hst) {
  __shared__ short sW[64 * 144];
  __shared__ short sX[128 * 40];
  __shared__ float scs[128];
  int tid = threadIdx.x;
  int ph = blockIdx.x, ch = blockIdx.y, b = blockIdx.z;
  int bc = b * NC + ch;
  size_t tb = (size_t)b * LSEQ + ch * CL;
  float Aval = -expf(alog[0]);
  if (tid < 128) scs[tid] = csumb[tb + tid];
  __syncthreads();
  float Stot = scs[127];
  {
    int s = tid >> 1, noff = (tid & 1) * 32;
    float scale = __expf(Aval * (Stot - scs[s]));
    #pragma unroll
    for (int blk = 0; blk < 4; ++blk) {
      bf16x8 v = *(const bf16x8*)&Bb[(tb + s) * DS + noff + blk * 8];
      #pragma unroll
      for (int e = 0; e < 8; ++e)
        sW[(noff + blk * 8 + e) * 144 + s] = (short)f2bf(bf2f((ushort_t)v[e]) * scale);
    }
  }
  int wave = tid >> 6, lane = tid & 63;
  int wn = (wave >> 1) * 32, wp = (wave & 1) * 64;
  int q = lane >> 4, c = lane & 15;
  f32x4 acc[2][4];
  #pragma unroll
  for (int i = 0; i < 2; ++i)
    #pragma unroll
    for (int j = 0; j < 4; ++j) acc[i][j] = (f32x4)0.f;

  for (int ks = 0; ks < 4; ++ks) {
    __syncthreads();
    {
      int r = tid >> 1, off = (tid & 1) * 16;
      size_t ua = ((size_t)b * DI + ph * 128 + r) * LSEQ + ch * CL + ks * 32 + off;
      bf16x8 u0 = *(const bf16x8*)&Ut[ua];
      bf16x8 u1 = *(const bf16x8*)&Ut[ua + 8];
      *(bf16x8*)&sX[r * 40 + off]     = u0;
      *(bf16x8*)&sX[r * 40 + off + 8] = u1;
    }
    __syncthreads();
    bf16x8 af[2], bfr[4];
    #pragma unroll
    for (int i = 0; i < 2; ++i)
      af[i] = *(const bf16x8*)&sW[(wn + i * 16 + c) * 144 + ks * 32 + q * 8];
    #pragma unroll
    for (int j = 0; j < 4; ++j)
      bfr[j] = *(const bf16x8*)&sX[(wp + j * 16 + c) * 40 + q * 8];
    #pragma unroll
    for (int i = 0; i < 2; ++i)
      #pragma unroll
      for (int j = 0; j < 4; ++j)
        acc[i][j] = __builtin_amdgcn_mfma_f32_16x16x32_bf16(af[i], bfr[j], acc[i][j], 0, 0, 0);
  }
  #pragma unroll
  for (int i = 0; i < 2; ++i) {
    int n = wn + i * 16 + q * 4;
    #pragma unroll
    for (int j = 0; j < 4; ++j) {
      int pg = ph * 128 + wp + j * 16 + c;
      #pragma unroll
      for (int r = 0; r < 4; ++r)
        hst[((size_t)bc * DS + n + r) * DI + pg] = acc[i][j][r];
    }
  }
}

// combine (unchanged, round-12)
__global__ __launch_bounds__(256) void combine2(const float* __restrict__ hst,
    const float* __restrict__ csumb, const float* __restrict__ alog,
    ushort_t* __restrict__ hin) {
  __shared__ ushort_t ts[64 * 17];
  int tid = threadIdx.x;
  int pt = blockIdx.x, nt = blockIdx.y, b = blockIdx.z;
  int p0 = pt * 64, n0 = nt * 16;
  int pl = tid & 63, ng = tid >> 6;
  float Aval = -expf(alog[0]);
  float h[4];
  #pragma unroll
  for (int i = 0; i < 4; ++i) h[i] = 0.f;
  for (int c = 0; c < NC; ++c) {
    int bc = b * NC + c;
    #pragma unroll
    for (int i = 0; i < 4; ++i)
      ts[pl * 17 + ng * 4 + i] = f2bf(h[i]);
    __syncthreads();
    {
      int on = tid & 15;
      #pragma unroll
      for (int pass = 0; pass < 4; ++pass) {
        int op = (tid >> 4) + pass * 16;
        hin[((size_t)bc * DI + p0 + op) * DS + n0 + on] = ts[op * 17 + on];
      }
    }
    __syncthreads();
    float Sc = csumb[(size_t)b * LSEQ + c * CL + CL - 1];
    float dec = __expf(Aval * Sc);
    #pragma unroll
    for (int i = 0; i < 4; ++i) {
      float loc = hst[((size_t)bc * DS + n0 + ng * 4 + i) * DI + p0 + pl];
      h[i] = h[i] * dec + loc;
    }
  }
}

// y GEMM (r12 base + double-buffered sU slices: ONE barrier per stage, 14->9).
__global__ __launch_bounds__(256) void y_gemm(const ushort_t* __restrict__ Bb,
    const ushort_t* __restrict__ Cb, const ushort_t* __restrict__ Ut,
    const ushort_t* __restrict__ hin, const float* __restrict__ csumb,
    const float* __restrict__ alog, const float* __restrict__ dpar,
    const ushort_t* __restrict__ xb, ushort_t* __restrict__ y) {
  __shared__ short sC[128 * 72];
  __shared__ short sM[128 * 136];
  __shared__ short sU[128 * 80];   // phase1: B rows str 80; phase2: 2 x (128 x 40) buffers
  __shared__ float scs[128];
  int tid = threadIdx.x;
  int ph = blockIdx.x, ch = blockIdx.y, b = blockIdx.z;
  int bc = b * NC + ch;
  size_t tb = (size_t)b * LSEQ + ch * CL;
  float Aval = -expf(alog[0]);
  float dp = dpar[0];
  int wave = tid >> 6, lane = tid & 63;
  int q = lane >> 4, c = lane & 15;

  {
    int r = tid >> 1, off = (tid & 1) * 32;
    #pragma unroll
    for (int blk = 0; blk < 4; ++blk) {
      *(bf16x8*)&sC[r * 72 + off + blk * 8] = *(const bf16x8*)&Cb[(tb + r) * DS + off + blk * 8];
      *(bf16x8*)&sU[r * 80 + off + blk * 8] = *(const bf16x8*)&Bb[(tb + r) * DS + off + blk * 8];
    }
  }
  if (tid < 128) scs[tid] = csumb[tb + tid];
  __syncthreads();

  // phase 1: G = C @ B^T (128t x 128s, K=64). Wave 1's block is fully masked.
  {
    int wm = (wave >> 1) * 64, wss = (wave & 1) * 64;
    if (wave == 1) {
      #pragma unroll
      for (int i = 0; i < 4; ++i) {
        #pragma unroll
        for (int r = 0; r < 4; ++r) {
          int t = i * 16 + q * 4 + r;
          #pragma unroll
          for (int j = 0; j < 4; ++j)
            sM[t * 136 + 64 + j * 16 + c] = 0;
        }
      }
    } else {
      f32x4 g[4][4];
      #pragma unroll
      for (int i = 0; i < 4; ++i)
        #pragma unroll
        for (int j = 0; j < 4; ++j) g[i][j] = (f32x4)0.f;
      #pragma unroll
      for (int k0 = 0; k0 < 64; k0 += 32) {
        bf16x8 af[4], bfr[4];
        #pragma unroll
        for (int i = 0; i < 4; ++i)
          af[i] = *(const bf16x8*)&sC[(wm + i * 16 + c) * 72 + k0 + q * 8];
        #pragma unroll
        for (int j = 0; j < 4; ++j)
          bfr[j] = *(const bf16x8*)&sU[(wss + j * 16 + c) * 80 + k0 + q * 8];
        #pragma unroll
        for (int i = 0; i < 4; ++i)
          #pragma unroll
          for (int j = 0; j < 4; ++j)
            g[i][j] = __builtin_amdgcn_mfma_f32_16x16x32_bf16(af[i], bfr[j], g[i][j], 0, 0, 0);
      }
      #pragma unroll
      for (int i = 0; i < 4; ++i) {
        #pragma unroll
        for (int r = 0; r < 4; ++r) {
          int t = wm + i * 16 + q * 4 + r;
          float ct = scs[t];
          #pragma unroll
          for (int j = 0; j < 4; ++j) {
            int s = wss + j * 16 + c;
            float v = g[i][j][r];
            float m = (s <= t) ? v * __expf(Aval * (ct - scs[s])) : 0.f;
            sM[t * 136 + s] = (short)f2bf(m);
          }
        }
      }
    }
  }
  __syncthreads();   // phase-1 LDS reads+writes complete (sU free, sM ready)

  // phase 2: Y (128t x 128p) = M @ U + Chat @ Hin. Double-buffered sU slices:
  // write buf[ks&1] -> barrier -> MFMA. Reads of buf[k] (stage k) finish
  // before stage k+1's barrier, so stage k+2 may overwrite it.
  int wm2 = (wave >> 1) * 64, wp = (wave & 1) * 64;
  int r2 = tid >> 1, off16 = (tid & 1) * 16;
  f32x4 acc[4][4];
  #pragma unroll
  for (int i = 0; i < 4; ++i)
    #pragma unroll
    for (int j = 0; j < 4; ++j) acc[i][j] = (f32x4)0.f;

  for (int ks = 0; ks < 4; ++ks) {
    short* buf = &sU[(ks & 1) * 128 * 40];
    {
      size_t ua = ((size_t)b * DI + ph * 128 + r2) * LSEQ + ch * CL + ks * 32 + off16;
      bf16x8 u0 = *(const bf16x8*)&Ut[ua];
      bf16x8 u1 = *(const bf16x8*)&Ut[ua + 8];
      *(bf16x8*)&buf[r2 * 40 + off16]     = u0;
      *(bf16x8*)&buf[r2 * 40 + off16 + 8] = u1;
    }
    __syncthreads();
    if (!(wm2 == 0 && ks >= 2)) {   // M upper-right quadrant is zero
      bf16x8 af[4], bfr[4];
      #pragma unroll
      for (int i = 0; i < 4; ++i)
        af[i] = *(const bf16x8*)&sM[(wm2 + i * 16 + c) * 136 + ks * 32 + q * 8];
      #pragma unroll
      for (int j = 0; j < 4; ++j)
        bfr[j] = *(const bf16x8*)&buf[(wp + j * 16 + c) * 40 + q * 8];
      #pragma unroll
      for (int i = 0; i < 4; ++i)
        #pragma unroll
        for (int j = 0; j < 4; ++j)
          acc[i][j] = __builtin_amdgcn_mfma_f32_16x16x32_bf16(af[i], bfr[j], acc[i][j], 0, 0, 0);
    }
  }

  __syncthreads();   // stage-3 sM reads done; safe to overwrite sM with Chat
  {
    int r = tid >> 1, off = (tid & 1) * 32;
    float sc_t = __expf(Aval * scs[r]);
    #pragma unroll
    for (int blk = 0; blk < 4; ++blk) {
      bf16x8 v = *(const bf16x8*)&sC[r * 72 + off + blk * 8];
      bf16x8 o;
      #pragma unroll
      for (int e = 0; e < 8; ++e)
        o[e] = (short)f2bf(bf2f((ushort_t)v[e]) * sc_t);
      *(bf16x8*)&sM[r * 80 + off + blk * 8] = o;
    }
  }
  for (int ks = 4; ks < 6; ++ks) {
    short* buf = &sU[(ks & 1) * 128 * 40];
    {
      size_t ha = ((size_t)bc * DI + ph * 128 + r2) * DS + (ks - 4) * 32 + off16;
      bf16x8 h0 = *(const bf16x8*)&hin[ha];
      bf16x8 h1 = *(const bf16x8*)&hin[ha + 8];
      *(bf16x8*)&buf[r2 * 40 + off16]     = h0;
      *(bf16x8*)&buf[r2 * 40 + off16 + 8] = h1;
    }
    __syncthreads();   // covers Chat sM writes (ks=4) and buf writes
    bf16x8 af[4], bfr[4];
    #pragma unroll
    for (int i = 0; i < 4; ++i)
      af[i] = *(const bf16x8*)&sM[(wm2 + i * 16 + c) * 80 + (ks - 4) * 32 + q * 8];
    #pragma unroll
    for (int j = 0; j < 4; ++j)
      bfr[j] = *(const bf16x8*)&buf[(wp + j * 16 + c) * 40 + q * 8];
    #pragma unroll
    for (int i = 0; i < 4; ++i)
      #pragma unroll
      for (int j = 0; j < 4; ++j)
        acc[i][j] = __builtin_amdgcn_mfma_f32_16x16x32_bf16(af[i], bfr[j], acc[i][j], 0, 0, 0);
  }

  #pragma unroll
  for (int i = 0; i < 4; ++i) {
    #pragma unroll
    for (int r = 0; r < 4; ++r) {
      int t = wm2 + i * 16 + q * 4 + r;
      size_t row = (tb + t) * DI;
      #pragma unroll
      for (int j = 0; j < 4; ++j) {
        int pg = ph * 128 + wp + j * 16 + c;
        y[row + pg] = f2bf(acc[i][j][r] + dp * bf2f(xb[row + pg]));
      }
    }
  }
}

// last token only: logits = hn_final @ embed[:100].T
__global__ __launch_bounds__(256) void finalize(const ushort_t* __restrict__ hn,
    const float* __restrict__ embed, float* __restrict__ out) {
  int b = blockIdx.x, tid = threadIdx.x;
  __shared__ float fin[DM];
  size_t off = ((size_t)b * LSEQ + (LSEQ - 1)) * DM;
  fin[tid] = bf2f(hn[off + tid]);
  __syncthreads();
  if (tid < VOC) {
    float acc = 0.f;
    #pragma unroll 8
    for (int d = 0; d < DM; ++d) acc += fin[d] * embed[(size_t)tid * DM + d];
    out[b * VOC + tid] = acc;
  }
}

extern "C" void kernel_launch(void* const* d_in, const int* in_sizes, int n_in,
                              void* d_out, int out_size, void* d_ws, size_t ws_size,
                              hipStream_t stream) {
  const int*   ids   = (const int*)d_in[0];
  const float* embed = (const float*)d_in[1];
  const float* ipw   = (const float*)d_in[2];
  const float* cw    = (const float*)d_in[3];
  const float* cb    = (const float*)d_in[4];
  const float* dtbias= (const float*)d_in[5];
  const float* alog  = (const float*)d_in[6];
  const float* dpar  = (const float*)d_in[7];
  const float* ngw   = (const float*)d_in[8];
  const float* opw   = (const float*)d_in[9];
  const float* bnw   = (const float*)d_in[10];
  const float* nfw   = (const float*)d_in[11];
  float* out = (float*)d_out;

  // workspace layout (~140 MB)
  char* p = (char*)d_ws;
  float* resid = (float*)p;            p += (size_t)TKN * DM * 4;
  ushort_t* hn = (ushort_t*)p;         p += (size_t)TKN * DM * 2;
  ushort_t* zx = (ushort_t*)p;         p += (size_t)TKN * DIPP * 2;
  float* dtb   = (float*)p;            p += (size_t)TKN * 4;
  float* csumb = (float*)p;            p += (size_t)TKN * 4;
  ushort_t* xb = (ushort_t*)p;         p += (size_t)TKN * DI * 2;
  ushort_t* yb = (ushort_t*)p;         p += (size_t)TKN * DI * 2;
  ushort_t* Bb = (ushort_t*)p;         p += (size_t)TKN * DS * 2;
  ushort_t* Cb = (ushort_t*)p;         p += (size_t)TKN * DS * 2;
  ushort_t* Ut = (ushort_t*)p;         p += (size_t)TKN * DI * 2;
  ushort_t* hin= (ushort_t*)p;         p += (size_t)NB * NC * DI * DS * 2;
  ushort_t* wbi= (ushort_t*)p;         p += (size_t)NL * DIP * DM * 2;
  ushort_t* wbo= (ushort_t*)p;         p += (size_t)NL * DM * DI * 2;
  // hst (fp32) aliases yb (bf16): consumed by combine2 before y_gemm writes yb
  float* hst = (float*)yb;

  convert_w<<<(NL * DIP * DM + NL * DM * DI + 1023) / 1024, 256, 0, stream>>>(
      ipw, opw, wbi, wbo);
  embed_rmsnorm<<<TKN / 4, 256, 0, stream>>>(resid, hn, bnw, ids, embed);

  for (int i = 0; i < NL; ++i) {
    gemm_nt_bf16<<<dim3((DIP + 127) / 128, TKN / 128), 256, 0, stream>>>(
        hn, wbi + (size_t)i * DIP * DM, zx, DIP, DM, DIPP);
    csum_k<<<32, 256, 0, stream>>>(zx, dtbias + i, dtb, csumb);
    conv_silu<<<dim3(CDIM / 128, LSEQ / 64, NB), 256, 0, stream>>>(
        zx, cw + (size_t)i * CDIM * 4, cb + (size_t)i * CDIM, dtb, xb, Bb, Cb, Ut);
    state_gemm<<<dim3(4, NC, NB), 256, 0, stream>>>(Bb, Ut, csumb, alog + i, hst);
    combine2<<<dim3(DI / 64, 4, NB), 256, 0, stream>>>(hst, csumb, alog + i, hin);
    y_gemm<<<dim3(4, NC, NB), 256, 0, stream>>>(Bb, Cb, Ut, hin, csumb, alog + i,
                                                dpar + i, xb, yb);
    const float* wnext = (i < NL - 1) ? (bnw + (size_t)(i + 1) * DM) : nfw;
    outproj_norm<<<TKN / 32, 256, 0, stream>>>(
        yb, zx, wbo + (size_t)i * DM * DI, ngw + (size_t)i * DI, resid, wnext, hn);
  }

  finalize<<<NB, 256, 0, stream>>>(hn, embed, out);
}

// Round 15
// 542.143 us; speedup vs baseline: 1.0655x; 1.0497x over previous
//
#include <hip/hip_runtime.h>
#include <math.h>

// ---- problem constants ----
#define NB    8        // batch
#define LSEQ  2048     // seq len
#define TKN   16384    // NB*LSEQ tokens
#define DM    256      // d_model
#define DI    512      // d_inner
#define DS    64       // d_state
#define DIP   1153     // 2*DI + 2*DS + 1
#define DIPP  1160     // padded row stride for zx (bf16)
#define CDIM  640      // DI + 2*DS
#define NL    4
#define NC    16       // scan chunks
#define CL    128      // LSEQ/NC
#define VOC   100

typedef short bf16x8 __attribute__((ext_vector_type(8)));
typedef short bf16x4 __attribute__((ext_vector_type(4)));
typedef float f32x4  __attribute__((ext_vector_type(4)));
typedef unsigned short ushort_t;

__device__ __forceinline__ unsigned short f2bf(float f) {
  unsigned int u = __float_as_uint(f);
  unsigned int r = u + 0x7FFFu + ((u >> 16) & 1u);   // RNE
  return (unsigned short)(r >> 16);
}
__device__ __forceinline__ float bf2f(unsigned short u) {
  return __uint_as_float(((unsigned int)u) << 16);
}

// prologue: weight bf16 conversion + embed gather + layer-0 rmsnorm, one dispatch.
// blocks [0, TKN/4): embed path (4 tokens/block); blocks [TKN/4, +1665): convert path.
__global__ __launch_bounds__(256) void prologue(const float* __restrict__ ipw,
    const float* __restrict__ opw, ushort_t* __restrict__ wbi, ushort_t* __restrict__ wbo,
    const int* __restrict__ ids, const float* __restrict__ embed,
    float* __restrict__ resid, ushort_t* __restrict__ hn, const float* __restrict__ w0) {
  int blk = blockIdx.x;
  if (blk < TKN / 4) {
    int wave = threadIdx.x >> 6, lane = threadIdx.x & 63;
    int t = blk * 4 + wave;
    size_t o = (size_t)t * DM + lane * 4;
    int id = ids[t];
    float4 r4 = *(const float4*)&embed[(size_t)id * DM + lane * 4];
    *(float4*)&resid[o] = r4;
    float ss = r4.x * r4.x + r4.y * r4.y + r4.z * r4.z + r4.w * r4.w;
    #pragma unroll
    for (int m = 32; m >= 1; m >>= 1) ss += __shfl_xor(ss, m, 64);
    float sc = rsqrtf(ss * (1.f / DM) + 1e-5f);
    float4 w4 = *(const float4*)&w0[lane * 4];
    bf16x4 o4;
    o4[0] = (short)f2bf(r4.x * sc * w4.x);
    o4[1] = (short)f2bf(r4.y * sc * w4.y);
    o4[2] = (short)f2bf(r4.z * sc * w4.z);
    o4[3] = (short)f2bf(r4.w * sc * w4.w);
    *(bf16x4*)&hn[o] = o4;
  } else {
    const int n1 = NL * DIP * DM;
    const int n2 = NL * DM * DI;
    int i4 = ((blk - TKN / 4) * 256 + threadIdx.x) * 4;
    if (i4 < n1) {
      float4 v = *(const float4*)(ipw + i4);
      bf16x4 o; o[0] = (short)f2bf(v.x); o[1] = (short)f2bf(v.y);
      o[2] = (short)f2bf(v.z); o[3] = (short)f2bf(v.w);
      *(bf16x4*)(wbi + i4) = o;
    } else {
      int j = i4 - n1;
      if (j < n2) {
        float4 v = *(const float4*)(opw + j);
        bf16x4 o; o[0] = (short)f2bf(v.x); o[1] = (short)f2bf(v.y);
        o[2] = (short)f2bf(v.z); o[3] = (short)f2bf(v.w);
        *(bf16x4*)(wbo + j) = o;
      }
    }
  }
}

// ---------------- bf16 MFMA GEMM (A bf16, B bf16), BK=64 ----------------
#define LSTR  40
#define LSTR2 72
__global__ __launch_bounds__(256) void gemm_nt_bf16(const ushort_t* __restrict__ A,
    const ushort_t* __restrict__ Bw, ushort_t* __restrict__ C, int N, int K, int ldc) {
  __shared__ short sA[128 * LSTR2];
  __shared__ short sB[128 * LSTR2];
  int tid = threadIdx.x;
  int bn = blockIdx.x * 128;
  int bm = blockIdx.y * 128;
  int wave = tid >> 6, lane = tid & 63;
  int wm = (wave >> 1) * 64, wn = (wave & 1) * 64;
  int q = lane >> 4, c = lane & 15;

  f32x4 acc[4][4];
  #pragma unroll
  for (int i = 0; i < 4; ++i)
    #pragma unroll
    for (int j = 0; j < 4; ++j) acc[i][j] = (f32x4)0.f;

  int sr = tid >> 1;
  int sc = (tid & 1) * 32;
  const ushort_t* Ag = A + (size_t)(bm + sr) * K + sc;
  const ushort_t* Bg = Bw + (size_t)(bn + sr) * K + sc;
  bool bok = (bn + sr) < N;
  short* sAp = &sA[sr * LSTR2 + sc];
  short* sBp = &sB[sr * LSTR2 + sc];

  for (int k0 = 0; k0 < K; k0 += 64) {
    bf16x8 a0 = *(const bf16x8*)(Ag + k0);
    bf16x8 a1 = *(const bf16x8*)(Ag + k0 + 8);
    bf16x8 a2 = *(const bf16x8*)(Ag + k0 + 16);
    bf16x8 a3 = *(const bf16x8*)(Ag + k0 + 24);
    bf16x8 b0 = (bf16x8)(short)0, b1 = (bf16x8)(short)0;
    bf16x8 b2 = (bf16x8)(short)0, b3 = (bf16x8)(short)0;
    if (bok) {
      b0 = *(const bf16x8*)(Bg + k0);
      b1 = *(const bf16x8*)(Bg + k0 + 8);
      b2 = *(const bf16x8*)(Bg + k0 + 16);
      b3 = *(const bf16x8*)(Bg + k0 + 24);
    }
    __syncthreads();
    *(bf16x8*)(sAp)      = a0;
    *(bf16x8*)(sAp + 8)  = a1;
    *(bf16x8*)(sAp + 16) = a2;
    *(bf16x8*)(sAp + 24) = a3;
    *(bf16x8*)(sBp)      = b0;
    *(bf16x8*)(sBp + 8)  = b1;
    *(bf16x8*)(sBp + 16) = b2;
    *(bf16x8*)(sBp + 24) = b3;
    __syncthreads();
    #pragma unroll
    for (int ks = 0; ks < 2; ++ks) {
      bf16x8 af[4], bfr[4];
      #pragma unroll
      for (int i = 0; i < 4; ++i)
        af[i] = *(const bf16x8*)&sA[(wm + i * 16 + c) * LSTR2 + ks * 32 + q * 8];
      #pragma unroll
      for (int j = 0; j < 4; ++j)
        bfr[j] = *(const bf16x8*)&sB[(wn + j * 16 + c) * LSTR2 + ks * 32 + q * 8];
      #pragma unroll
      for (int i = 0; i < 4; ++i)
        #pragma unroll
        for (int j = 0; j < 4; ++j)
          acc[i][j] = __builtin_amdgcn_mfma_f32_16x16x32_bf16(af[i], bfr[j], acc[i][j], 0, 0, 0);
    }
  }
  #pragma unroll
  for (int i = 0; i < 4; ++i) {
    int m = bm + wm + i * 16 + q * 4;
    #pragma unroll
    for (int j = 0; j < 4; ++j) {
      int n = bn + wn + j * 16 + c;
      if (n < N) {
        #pragma unroll
        for (int r = 0; r < 4; ++r)
          C[(size_t)(m + r) * ldc + n] = f2bf(acc[i][j][r]);
      }
    }
  }
}

// fused out_proj + residual-add + next-layer rmsnorm. (unchanged, round-12)
__global__ __launch_bounds__(256) void outproj_norm(const ushort_t* __restrict__ yb,
    const ushort_t* __restrict__ zx, const ushort_t* __restrict__ Bw,
    const float* __restrict__ gw, float* __restrict__ resid,
    const float* __restrict__ wnext, ushort_t* __restrict__ hn) {
  __shared__ short sA[32 * LSTR];
  __shared__ short sB[256 * LSTR];
  __shared__ float swl[DI];
  __shared__ float swn[DM];
  __shared__ float rs[128];
  __shared__ float rs2[32 * 2];
  int tid = threadIdx.x;
  int bm = blockIdx.x * 32;
  int wave = tid >> 6, lane = tid & 63;
  int wm = (wave >> 1) * 16, wn = (wave & 1) * 128;
  int q = lane >> 4, c = lane & 15;
  swl[tid] = gw[tid];
  swl[tid + 256] = gw[tid + 256];
  swn[tid] = wnext[tid];

  f32x4 acc[8];
  #pragma unroll
  for (int j = 0; j < 8; ++j) acc[j] = (f32x4)0.f;

  int ar = tid >> 2, ak = (tid & 3) * 8;
  bool isa = tid < 128;
  const ushort_t* yrow = yb + (size_t)(bm + ar) * DI + ak;
  const ushort_t* zrow = zx + (size_t)(bm + ar) * DIPP + ak;
  const ushort_t* Bg = Bw + (size_t)tid * DI;
  float sumsq = 0.f;
  __syncthreads();

  for (int k0 = 0; k0 < DI; k0 += 32) {
    bf16x8 g8;
    if (isa) {
      bf16x8 y8 = *(const bf16x8*)(yrow + k0);
      bf16x8 z8 = *(const bf16x8*)(zrow + k0);
      #pragma unroll
      for (int e = 0; e < 8; ++e) {
        float zz = bf2f((ushort_t)z8[e]);
        float gg = bf2f((ushort_t)y8[e]) * (zz / (1.f + __expf(-zz)));
        sumsq += gg * gg;
        g8[e] = (short)f2bf(gg * swl[k0 + ak + e]);
      }
    }
    bf16x8 b0 = *(const bf16x8*)(Bg + k0);
    bf16x8 b1 = *(const bf16x8*)(Bg + k0 + 8);
    bf16x8 b2 = *(const bf16x8*)(Bg + k0 + 16);
    bf16x8 b3 = *(const bf16x8*)(Bg + k0 + 24);
    __syncthreads();
    if (isa) *(bf16x8*)&sA[ar * LSTR + ak] = g8;
    *(bf16x8*)&sB[tid * LSTR]      = b0;
    *(bf16x8*)&sB[tid * LSTR + 8]  = b1;
    *(bf16x8*)&sB[tid * LSTR + 16] = b2;
    *(bf16x8*)&sB[tid * LSTR + 24] = b3;
    __syncthreads();
    bf16x8 af = *(const bf16x8*)&sA[(wm + c) * LSTR + q * 8];
    #pragma unroll
    for (int j = 0; j < 8; ++j) {
      bf16x8 bfr = *(const bf16x8*)&sB[(wn + j * 16 + c) * LSTR + q * 8];
      acc[j] = __builtin_amdgcn_mfma_f32_16x16x32_bf16(af, bfr, acc[j], 0, 0, 0);
    }
  }
  if (isa) rs[tid] = sumsq;
  __syncthreads();

  float outv[8][4];
  float sq2[4];
  #pragma unroll
  for (int r = 0; r < 4; ++r) {
    int row = wm + q * 4 + r;
    float s1 = rsqrtf((rs[row * 4] + rs[row * 4 + 1] + rs[row * 4 + 2] + rs[row * 4 + 3])
                      * (1.f / DI) + 1e-5f);
    float sq = 0.f;
    #pragma unroll
    for (int j = 0; j < 8; ++j) {
      int col = wn + j * 16 + c;
      size_t ro = (size_t)(bm + row) * DM + col;
      float rn = resid[ro] + s1 * acc[j][r];
      resid[ro] = rn;
      outv[j][r] = rn;
      sq += rn * rn;
    }
    sq2[r] = sq;
  }
  #pragma unroll
  for (int r = 0; r < 4; ++r) {
    #pragma unroll
    for (int m = 1; m <= 8; m <<= 1) sq2[r] += __shfl_xor(sq2[r], m, 64);
  }
  if (c == 0) {
    #pragma unroll
    for (int r = 0; r < 4; ++r)
      rs2[(wm + q * 4 + r) * 2 + (wave & 1)] = sq2[r];
  }
  __syncthreads();
  #pragma unroll
  for (int r = 0; r < 4; ++r) {
    int row = wm + q * 4 + r;
    float s2 = rsqrtf((rs2[row * 2] + rs2[row * 2 + 1]) * (1.f / DM) + 1e-5f);
    #pragma unroll
    for (int j = 0; j < 8; ++j) {
      int col = wn + j * 16 + c;
      hn[(size_t)(bm + row) * DM + col] = f2bf(outv[j][r] * s2 * swn[col]);
    }
  }
}

// LDS-tiled conv(4)+bias+silu + fused U^T transpose (Ut = x^T, dt folded into
// W/M now) + fused csum (ct==5 blocks: softplus+prefix-scan of dt).
// grid (6, LSEQ/64, NB), block 256.
__global__ __launch_bounds__(256) void conv_silu(const ushort_t* __restrict__ zx,
    const float* __restrict__ cw, const float* __restrict__ cb,
    const float* __restrict__ dtbias, ushort_t* __restrict__ xo,
    ushort_t* __restrict__ Bo, ushort_t* __restrict__ Co, ushort_t* __restrict__ Ut,
    float* __restrict__ dtb, float* __restrict__ csumb) {
  __shared__ ushort_t tile[67 * 128];
  __shared__ ushort_t tt[128 * 72];
  int tid = threadIdx.x;
  int ct = blockIdx.x, tb_ = blockIdx.y, b = blockIdx.z;
  size_t rowb = (size_t)b * LSEQ;
  if (ct == 5) {
    // csum blocks: tb_ < 16 -> chunk tb_; one wave does the 128-step scan.
    if (tb_ < 16 && tid < 64) {
      int lane = tid;
      size_t base = rowb + (size_t)tb_ * CL;
      float bias = dtbias[0];
      float x0 = bf2f(zx[(base + 2 * lane) * DIPP + (DIP - 1)]) + bias;
      float x1 = bf2f(zx[(base + 2 * lane + 1) * DIPP + (DIP - 1)]) + bias;
      float d0 = (x0 > 20.f) ? x0 : log1pf(__expf(x0));
      float d1 = (x1 > 20.f) ? x1 : log1pf(__expf(x1));
      dtb[base + 2 * lane] = d0;
      dtb[base + 2 * lane + 1] = d1;
      float p = d0 + d1;
      #pragma unroll
      for (int off = 1; off < 64; off <<= 1) {
        float t = __shfl_up(p, off, 64);
        if (lane >= off) p += t;
      }
      csumb[base + 2 * lane]     = p - d1;
      csumb[base + 2 * lane + 1] = p;
    }
    return;
  }
  int c0 = ct * 128, l0 = tb_ * 64;
  bool isx = (ct < 4);
  for (int slot = tid; slot < 67 * 16; slot += 256) {
    int r = slot >> 4, gg = slot & 15;
    int l = l0 + r - 3;
    bf16x8 v = (bf16x8)(short)0;
    if (l >= 0) v = *(const bf16x8*)&zx[(rowb + l) * DIPP + DI + c0 + gg * 8];
    *(bf16x8*)&tile[r * 128 + gg * 8] = v;
  }
  int g = tid & 15, tq = tid >> 4;
  int cbase = c0 + g * 8;
  float w[4][8], bias[8];
  #pragma unroll
  for (int e = 0; e < 8; ++e) {
    float4 wv = *(const float4*)&cw[(cbase + e) * 4];
    w[0][e] = wv.x; w[1][e] = wv.y; w[2][e] = wv.z; w[3][e] = wv.w;
    bias[e] = cb[cbase + e];
  }
  __syncthreads();
  bf16x8 rows[7];
  #pragma unroll
  for (int r = 0; r < 7; ++r)
    rows[r] = *(const bf16x8*)&tile[(tq * 4 + r) * 128 + g * 8];
  #pragma unroll
  for (int it = 0; it < 4; ++it) {
    int t = tq * 4 + it;
    size_t tl = rowb + l0 + t;
    bf16x8 o;
    #pragma unroll
    for (int e = 0; e < 8; ++e) {
      float s = bias[e]
              + w[0][e] * bf2f((ushort_t)rows[it][e])
              + w[1][e] * bf2f((ushort_t)rows[it + 1][e])
              + w[2][e] * bf2f((ushort_t)rows[it + 2][e])
              + w[3][e] * bf2f((ushort_t)rows[it + 3][e]);
      float v = s / (1.f + __expf(-s));
      o[e] = (short)f2bf(v);
      if (isx) tt[(g * 8 + e) * 72 + t] = (ushort_t)o[e];
    }
    if (isx) {
      *(bf16x8*)&xo[tl * DI + cbase] = o;
    } else if (g < 8) {
      *(bf16x8*)&Bo[tl * DS + (cbase - DI)] = o;
    } else {
      *(bf16x8*)&Co[tl * DS + (cbase - DI - DS)] = o;
    }
  }
  if (isx) {
    __syncthreads();
    #pragma unroll
    for (int pass = 0; pass < 4; ++pass) {
      int slot = pass * 256 + tid;
      int op = slot >> 3, sg = slot & 7;
      bf16x8 v = *(const bf16x8*)&tt[op * 72 + sg * 8];
      *(bf16x8*)&Ut[((size_t)b * DI + c0 + op) * LSEQ + l0 + sg * 8] = v;
    }
  }
}

// state GEMM: Hloc[bc][n][p] = sum_s exp(A(S-cs[s]))*dt[s] * B[s][n] * x[s][p]
// (dt folded into W). Otherwise r12/r9 structure.
__global__ __launch_bounds__(256) void state_gemm(const ushort_t* __restrict__ Bb,
    const ushort_t* __restrict__ Ut, const float* __restrict__ csumb,
    const float* __restrict__ dtb, const float* __restrict__ alog,
    float* __restrict__ hst) {
  __shared__ short sW[64 * 144];
  __shared__ short sX[128 * 40];
  __shared__ float scs[128];
  __shared__ float sdt[128];
  int tid = threadIdx.x;
  int ph = blockIdx.x, ch = blockIdx.y, b = blockIdx.z;
  int bc = b * NC + ch;
  size_t tb = (size_t)b * LSEQ + ch * CL;
  float Aval = -expf(alog[0]);
  if (tid < 128) { scs[tid] = csumb[tb + tid]; sdt[tid] = dtb[tb + tid]; }
  __syncthreads();
  float Stot = scs[127];
  {
    int s = tid >> 1, noff = (tid & 1) * 32;
    float scale = __expf(Aval * (Stot - scs[s])) * sdt[s];
    #pragma unroll
    for (int blk = 0; blk < 4; ++blk) {
      bf16x8 v = *(const bf16x8*)&Bb[(tb + s) * DS + noff + blk * 8];
      #pragma unroll
      for (int e = 0; e < 8; ++e)
        sW[(noff + blk * 8 + e) * 144 + s] = (short)f2bf(bf2f((ushort_t)v[e]) * scale);
    }
  }
  int wave = tid >> 6, lane = tid & 63;
  int wn = (wave >> 1) * 32, wp = (wave & 1) * 64;
  int q = lane >> 4, c = lane & 15;
  f32x4 acc[2][4];
  #pragma unroll
  for (int i = 0; i < 2; ++i)
    #pragma unroll
    for (int j = 0; j < 4; ++j) acc[i][j] = (f32x4)0.f;

  for (int ks = 0; ks < 4; ++ks) {
    __syncthreads();
    {
      int r = tid >> 1, off = (tid & 1) * 16;
      size_t ua = ((size_t)b * DI + ph * 128 + r) * LSEQ + ch * CL + ks * 32 + off;
      bf16x8 u0 = *(const bf16x8*)&Ut[ua];
      bf16x8 u1 = *(const bf16x8*)&Ut[ua + 8];
      *(bf16x8*)&sX[r * 40 + off]     = u0;
      *(bf16x8*)&sX[r * 40 + off + 8] = u1;
    }
    __syncthreads();
    bf16x8 af[2], bfr[4];
    #pragma unroll
    for (int i = 0; i < 2; ++i)
      af[i] = *(const bf16x8*)&sW[(wn + i * 16 + c) * 144 + ks * 32 + q * 8];
    #pragma unroll
    for (int j = 0; j < 4; ++j)
      bfr[j] = *(const bf16x8*)&sX[(wp + j * 16 + c) * 40 + q * 8];
    #pragma unroll
    for (int i = 0; i < 2; ++i)
      #pragma unroll
      for (int j = 0; j < 4; ++j)
        acc[i][j] = __builtin_amdgcn_mfma_f32_16x16x32_bf16(af[i], bfr[j], acc[i][j], 0, 0, 0);
  }
  #pragma unroll
  for (int i = 0; i < 2; ++i) {
    int n = wn + i * 16 + q * 4;
    #pragma unroll
    for (int j = 0; j < 4; ++j) {
      int pg = ph * 128 + wp + j * 16 + c;
      #pragma unroll
      for (int r = 0; r < 4; ++r)
        hst[((size_t)bc * DS + n + r) * DI + pg] = acc[i][j][r];
    }
  }
}

// combine (unchanged)
__global__ __launch_bounds__(256) void combine2(const float* __restrict__ hst,
    const float* __restrict__ csumb, const float* __restrict__ alog,
    ushort_t* __restrict__ hin) {
  __shared__ ushort_t ts[64 * 17];
  int tid = threadIdx.x;
  int pt = blockIdx.x, nt = blockIdx.y, b = blockIdx.z;
  int p0 = pt * 64, n0 = nt * 16;
  int pl = tid & 63, ng = tid >> 6;
  float Aval = -expf(alog[0]);
  float h[4];
  #pragma unroll
  for (int i = 0; i < 4; ++i) h[i] = 0.f;
  for (int c = 0; c < NC; ++c) {
    int bc = b * NC + c;
    #pragma unroll
    for (int i = 0; i < 4; ++i)
      ts[pl * 17 + ng * 4 + i] = f2bf(h[i]);
    __syncthreads();
    {
      int on = tid & 15;
      #pragma unroll
      for (int pass = 0; pass < 4; ++pass) {
        int op = (tid >> 4) + pass * 16;
        hin[((size_t)bc * DI + p0 + op) * DS + n0 + on] = ts[op * 17 + on];
      }
    }
    __syncthreads();
    float Sc = csumb[(size_t)b * LSEQ + c * CL + CL - 1];
    float dec = __expf(Aval * Sc);
    #pragma unroll
    for (int i = 0; i < 4; ++i) {
      float loc = hst[((size_t)bc * DS + n0 + ng * 4 + i) * DI + p0 + pl];
      h[i] = h[i] * dec + loc;
    }
  }
}

// y GEMM — exact r12 (562us) structure; only change: dt[s] folded into M.
__global__ __launch_bounds__(256) void y_gemm(const ushort_t* __restrict__ Bb,
    const ushort_t* __restrict__ Cb, const ushort_t* __restrict__ Ut,
    const ushort_t* __restrict__ hin, const float* __restrict__ csumb,
    const float* __restrict__ dtb, const float* __restrict__ alog,
    const float* __restrict__ dpar, const ushort_t* __restrict__ xb,
    ushort_t* __restrict__ y) {
  __shared__ short sC[128 * 72];
  __shared__ short sM[128 * 136];
  __shared__ short sU[128 * 80];
  __shared__ float scs[128];
  __shared__ float sdt[128];
  int tid = threadIdx.x;
  int ph = blockIdx.x, ch = blockIdx.y, b = blockIdx.z;
  int bc = b * NC + ch;
  size_t tb = (size_t)b * LSEQ + ch * CL;
  float Aval = -expf(alog[0]);
  float dp = dpar[0];
  int wave = tid >> 6, lane = tid & 63;
  int q = lane >> 4, c = lane & 15;

  {
    int r = tid >> 1, off = (tid & 1) * 32;
    #pragma unroll
    for (int blk = 0; blk < 4; ++blk) {
      *(bf16x8*)&sC[r * 72 + off + blk * 8] = *(const bf16x8*)&Cb[(tb + r) * DS + off + blk * 8];
      *(bf16x8*)&sU[r * 80 + off + blk * 8] = *(const bf16x8*)&Bb[(tb + r) * DS + off + blk * 8];
    }
  }
  if (tid < 128) { scs[tid] = csumb[tb + tid]; sdt[tid] = dtb[tb + tid]; }
  __syncthreads();

  // phase 1: G = C @ B^T (128t x 128s, K=64). Wave 1's block is fully masked.
  {
    int wm = (wave >> 1) * 64, wss = (wave & 1) * 64;
    if (wave == 1) {
      #pragma unroll
      for (int i = 0; i < 4; ++i) {
        #pragma unroll
        for (int r = 0; r < 4; ++r) {
          int t = i * 16 + q * 4 + r;
          #pragma unroll
          for (int j = 0; j < 4; ++j)
            sM[t * 136 + 64 + j * 16 + c] = 0;
        }
      }
    } else {
      f32x4 g[4][4];
      #pragma unroll
      for (int i = 0; i < 4; ++i)
        #pragma unroll
        for (int j = 0; j < 4; ++j) g[i][j] = (f32x4)0.f;
      #pragma unroll
      for (int k0 = 0; k0 < 64; k0 += 32) {
        bf16x8 af[4], bfr[4];
        #pragma unroll
        for (int i = 0; i < 4; ++i)
          af[i] = *(const bf16x8*)&sC[(wm + i * 16 + c) * 72 + k0 + q * 8];
        #pragma unroll
        for (int j = 0; j < 4; ++j)
          bfr[j] = *(const bf16x8*)&sU[(wss + j * 16 + c) * 80 + k0 + q * 8];
        #pragma unroll
        for (int i = 0; i < 4; ++i)
          #pragma unroll
          for (int j = 0; j < 4; ++j)
            g[i][j] = __builtin_amdgcn_mfma_f32_16x16x32_bf16(af[i], bfr[j], g[i][j], 0, 0, 0);
      }
      float dts[4];
      #pragma unroll
      for (int j = 0; j < 4; ++j) dts[j] = sdt[wss + j * 16 + c];
      #pragma unroll
      for (int i = 0; i < 4; ++i) {
        #pragma unroll
        for (int r = 0; r < 4; ++r) {
          int t = wm + i * 16 + q * 4 + r;
          float ct = scs[t];
          #pragma unroll
          for (int j = 0; j < 4; ++j) {
            int s = wss + j * 16 + c;
            float v = g[i][j][r];
            float m = (s <= t) ? v * __expf(Aval * (ct - scs[s])) * dts[j] : 0.f;
            sM[t * 136 + s] = (short)f2bf(m);
          }
        }
      }
    }
  }

  // phase 2: Y (128t x 128p) = M @ X^T + Chat @ Hin
  int wm2 = (wave >> 1) * 64, wp = (wave & 1) * 64;
  f32x4 acc[4][4];
  #pragma unroll
  for (int i = 0; i < 4; ++i)
    #pragma unroll
    for (int j = 0; j < 4; ++j) acc[i][j] = (f32x4)0.f;

  for (int ks = 0; ks < 4; ++ks) {
    __syncthreads();
    {
      int r = tid >> 1, off = (tid & 1) * 16;
      size_t ua = ((size_t)b * DI + ph * 128 + r) * LSEQ + ch * CL + ks * 32 + off;
      bf16x8 u0 = *(const bf16x8*)&Ut[ua];
      bf16x8 u1 = *(const bf16x8*)&Ut[ua + 8];
      *(bf16x8*)&sU[r * 40 + off]     = u0;
      *(bf16x8*)&sU[r * 40 + off + 8] = u1;
    }
    __syncthreads();
    if (!(wm2 == 0 && ks >= 2)) {   // M upper-right quadrant is zero
      bf16x8 af[4], bfr[4];
      #pragma unroll
      for (int i = 0; i < 4; ++i)
        af[i] = *(const bf16x8*)&sM[(wm2 + i * 16 + c) * 136 + ks * 32 + q * 8];
      #pragma unroll
      for (int j = 0; j < 4; ++j)
        bfr[j] = *(const bf16x8*)&sU[(wp + j * 16 + c) * 40 + q * 8];
      #pragma unroll
      for (int i = 0; i < 4; ++i)
        #pragma unroll
        for (int j = 0; j < 4; ++j)
          acc[i][j] = __builtin_amdgcn_mfma_f32_16x16x32_bf16(af[i], bfr[j], acc[i][j], 0, 0, 0);
    }
  }

  __syncthreads();
  {
    int r = tid >> 1, off = (tid & 1) * 32;
    float sc_t = __expf(Aval * scs[r]);
    #pragma unroll
    for (int blk = 0; blk < 4; ++blk) {
      bf16x8 v = *(const bf16x8*)&sC[r * 72 + off + blk * 8];
      bf16x8 o;
      #pragma unroll
      for (int e = 0; e < 8; ++e)
        o[e] = (short)f2bf(bf2f((ushort_t)v[e]) * sc_t);
      *(bf16x8*)&sM[r * 80 + off + blk * 8] = o;
    }
  }
  for (int ks = 4; ks < 6; ++ks) {
    __syncthreads();
    {
      int r = tid >> 1, off = (tid & 1) * 16;
      size_t ha = ((size_t)bc * DI + ph * 128 + r) * DS + (ks - 4) * 32 + off;
      bf16x8 h0 = *(const bf16x8*)&hin[ha];
      bf16x8 h1 = *(const bf16x8*)&hin[ha + 8];
      *(bf16x8*)&sU[r * 40 + off]     = h0;
      *(bf16x8*)&sU[r * 40 + off + 8] = h1;
    }
    __syncthreads();
    bf16x8 af[4], bfr[4];
    #pragma unroll
    for (int i = 0; i < 4; ++i)
      af[i] = *(const bf16x8*)&sM[(wm2 + i * 16 + c) * 80 + (ks - 4) * 32 + q * 8];
    #pragma unroll
    for (int j = 0; j < 4; ++j)
      bfr[j] = *(const bf16x8*)&sU[(wp + j * 16 + c) * 40 + q * 8];
    #pragma unroll
    for (int i = 0; i < 4; ++i)
      #pragma unroll
      for (int j = 0; j < 4; ++j)
        acc[i][j] = __builtin_amdgcn_mfma_f32_16x16x32_bf16(af[i], bfr[j], acc[i][j], 0, 0, 0);
  }

  #pragma unroll
  for (int i = 0; i < 4; ++i) {
    #pragma unroll
    for (int r = 0; r < 4; ++r) {
      int t = wm2 + i * 16 + q * 4 + r;
      size_t row = (tb + t) * DI;
      #pragma unroll
      for (int j = 0; j < 4; ++j) {
        int pg = ph * 128 + wp + j * 16 + c;
        y[row + pg] = f2bf(acc[i][j][r] + dp * bf2f(xb[row + pg]));
      }
    }
  }
}

// last token only: logits = hn_final @ embed[:100].T
__global__ __launch_bounds__(256) void finalize(const ushort_t* __restrict__ hn,
    const float* __restrict__ embed, float* __restrict__ out) {
  int b = blockIdx.x, tid = threadIdx.x;
  __shared__ float fin[DM];
  size_t off = ((size_t)b * LSEQ + (LSEQ - 1)) * DM;
  fin[tid] = bf2f(hn[off + tid]);
  __syncthreads();
  if (tid < VOC) {
    float acc = 0.f;
    #pragma unroll 8
    for (int d = 0; d < DM; ++d) acc += fin[d] * embed[(size_t)tid * DM + d];
    out[b * VOC + tid] = acc;
  }
}

extern "C" void kernel_launch(void* const* d_in, const int* in_sizes, int n_in,
                              void* d_out, int out_size, void* d_ws, size_t ws_size,
                              hipStream_t stream) {
  const int*   ids   = (const int*)d_in[0];
  const float* embed = (const float*)d_in[1];
  const float* ipw   = (const float*)d_in[2];
  const float* cw    = (const float*)d_in[3];
  const float* cb    = (const float*)d_in[4];
  const float* dtbias= (const float*)d_in[5];
  const float* alog  = (const float*)d_in[6];
  const float* dpar  = (const float*)d_in[7];
  const float* ngw   = (const float*)d_in[8];
  const float* opw   = (const float*)d_in[9];
  const float* bnw   = (const float*)d_in[10];
  const float* nfw   = (const float*)d_in[11];
  float* out = (float*)d_out;

  // workspace layout (~140 MB)
  char* p = (char*)d_ws;
  float* resid = (float*)p;            p += (size_t)TKN * DM * 4;
  ushort_t* hn = (ushort_t*)p;         p += (size_t)TKN * DM * 2;
  ushort_t* zx = (ushort_t*)p;         p += (size_t)TKN * DIPP * 2;
  float* dtb   = (float*)p;            p += (size_t)TKN * 4;
  float* csumb = (float*)p;            p += (size_t)TKN * 4;
  ushort_t* xb = (ushort_t*)p;         p += (size_t)TKN * DI * 2;
  ushort_t* yb = (ushort_t*)p;         p += (size_t)TKN * DI * 2;
  ushort_t* Bb = (ushort_t*)p;         p += (size_t)TKN * DS * 2;
  ushort_t* Cb = (ushort_t*)p;         p += (size_t)TKN * DS * 2;
  ushort_t* Ut = (ushort_t*)p;         p += (size_t)TKN * DI * 2;
  ushort_t* hin= (ushort_t*)p;         p += (size_t)NB * NC * DI * DS * 2;
  ushort_t* wbi= (ushort_t*)p;         p += (size_t)NL * DIP * DM * 2;
  ushort_t* wbo= (ushort_t*)p;         p += (size_t)NL * DM * DI * 2;
  // hst (fp32) aliases yb (bf16): consumed by combine2 before y_gemm writes yb
  float* hst = (float*)yb;

  const int convblks = (NL * DIP * DM + NL * DM * DI + 1023) / 1024;  // 1665
  prologue<<<TKN / 4 + convblks, 256, 0, stream>>>(ipw, opw, wbi, wbo,
                                                   ids, embed, resid, hn, bnw);

  for (int i = 0; i < NL; ++i) {
    gemm_nt_bf16<<<dim3((DIP + 127) / 128, TKN / 128), 256, 0, stream>>>(
        hn, wbi + (size_t)i * DIP * DM, zx, DIP, DM, DIPP);
    conv_silu<<<dim3(6, LSEQ / 64, NB), 256, 0, stream>>>(
        zx, cw + (size_t)i * CDIM * 4, cb + (size_t)i * CDIM, dtbias + i,
        xb, Bb, Cb, Ut, dtb, csumb);
    state_gemm<<<dim3(4, NC, NB), 256, 0, stream>>>(Bb, Ut, csumb, dtb, alog + i, hst);
    combine2<<<dim3(DI / 64, 4, NB), 256, 0, stream>>>(hst, csumb, alog + i, hin);
    y_gemm<<<dim3(4, NC, NB), 256, 0, stream>>>(Bb, Cb, Ut, hin, csumb, dtb,
                                                alog + i, dpar + i, xb, yb);
    const float* wnext = (i < NL - 1) ? (bnw + (size_t)(i + 1) * DM) : nfw;
    outproj_norm<<<TKN / 32, 256, 0, stream>>>(
        yb, zx, wbo + (size_t)i * DM * DI, ngw + (size_t)i * DI, resid, wnext, hn);
  }

  finalize<<<NB, 256, 0, stream>>>(hn, embed, out);
}